// Round 1
// baseline (2062.850 us; speedup 1.0000x reference)
//
#include <hip/hip_runtime.h>
#include <hip/hip_bf16.h>
#include <cstdint>
#include <cstdio>
#include <math.h>

// ---------------- problem constants ----------------
#define S_TOK 16384     // B*SEQ
#define E_EXP 8
#define DDIM  1024
#define HDIM  4096
#define K_SEL 32768     // int(S * 2.0)
#define ES    131072    // E * S
#define OUT_XO 16777216 // S*D

// ---------------- workspace layout (bytes) ----------------
#define WS_HIST1   0x000000u   // 65536 u32
#define WS_HIST2   0x040000u   // 65536 u32
#define WS_META    0x080000u   // meta[0]=b_hi [1]=cnt_above [2]=t_bits [3]=cgt [4]=need [5]=tie_cnt
#define WS_COUNTS  0x080400u   // 8 u32
#define WS_EXOFF   0x080500u   // 9 u32
#define WS_TIEIDX  0x080800u   // 8192 u32
#define WS_TOK     0x0A0000u   // E*S int
#define WS_COEF    0x120000u   // E*S float
#define WS_SCORES  0x1A0000u   // E*S float
#define WS_XB      0x400000u   // S*D bf16 (32MB)
#define WS_W1T    0x2400000u   // E*H*D bf16 (64MB)
#define WS_W2T    0x6400000u   // E*D*H bf16 (64MB)
#define WS_HBUF   0xA400000u   // K_SEL*H bf16 (256MB)
#define WS_TOTAL  0x1A400000u  // ~420MB
#define WS_CLEAR   0x080800u

typedef __attribute__((ext_vector_type(4))) float f32x4;
typedef __attribute__((ext_vector_type(8))) short bf16x8;

__device__ __forceinline__ void gload_lds16(const void* g, void* l) {
  __builtin_amdgcn_global_load_lds((const __attribute__((address_space(1))) void*)g,
                                   (__attribute__((address_space(3))) void*)l, 16, 0, 0);
}

__device__ __forceinline__ float gelu_f(float x) {
  float x3 = x * x * x;
  float u = 0.7978845608028654f * (x + 0.044715f * x3);
  return 0.5f * x * (1.0f + tanhf(u));
}

// ---------------- weight transpose + fp32->bf16 ----------------
// in: [E][R][C] fp32 ; out: [E][C][R] bf16
__global__ __launch_bounds__(256) void transpose_bf16_kernel(
    const float* __restrict__ in, __hip_bfloat16* __restrict__ outp, int R, int C)
{
  __shared__ float tile[32][33];
  const int c0 = blockIdx.x * 32, r0 = blockIdx.y * 32;
  const size_t eoff = (size_t)blockIdx.z * (size_t)R * (size_t)C;
  const float* ip = in + eoff;
  __hip_bfloat16* op = outp + eoff;
  const int tx = threadIdx.x, ty = threadIdx.y;
#pragma unroll
  for (int i = 0; i < 4; i++) {
    int r = ty + i * 8;
    tile[r][tx] = ip[(size_t)(r0 + r) * C + c0 + tx];
  }
  __syncthreads();
#pragma unroll
  for (int i = 0; i < 4; i++) {
    int c = ty + i * 8;
    op[(size_t)(c0 + c) * R + r0 + tx] = __float2bfloat16(tile[tx][c]);
  }
}

// ---------------- router: scores + x->bf16 + hi-16 histogram ----------------
__global__ __launch_bounds__(256) void router_kernel(
    const float* __restrict__ x, const float* __restrict__ gw, const float* __restrict__ bias,
    float* __restrict__ scores, __hip_bfloat16* __restrict__ xb, unsigned* __restrict__ hist1)
{
  __shared__ float g[E_EXP * DDIM];
  __shared__ float bs[E_EXP];
  const int tid = threadIdx.x;
  for (int i = tid; i < E_EXP * DDIM; i += 256) g[i] = gw[i];
  if (tid < E_EXP) bs[tid] = bias[tid];
  __syncthreads();
  const int w = tid >> 6, lane = tid & 63;
  const int s = blockIdx.x * 4 + w;
  double acc[E_EXP] = {0, 0, 0, 0, 0, 0, 0, 0};
  const float* xrow = x + (size_t)s * DDIM;
  __hip_bfloat16* xbrow = xb + (size_t)s * DDIM;
#pragma unroll 4
  for (int j = 0; j < 16; j++) {
    int d = lane + 64 * j;
    float xv = xrow[d];
    xbrow[d] = __float2bfloat16(xv);
#pragma unroll
    for (int e = 0; e < E_EXP; e++) acc[e] += (double)xv * (double)g[e * DDIM + d];
  }
#pragma unroll
  for (int e = 0; e < E_EXP; e++) {
    double a = acc[e];
#pragma unroll
    for (int off = 32; off > 0; off >>= 1) a += __shfl_xor(a, off);
    acc[e] = a;
  }
  if (lane == 0) {
#pragma unroll
    for (int e = 0; e < E_EXP; e++) {
      double lg = acc[e] + (double)bs[e];
      float sc = (float)(1.0 / (1.0 + exp(-lg)));
      scores[(size_t)e * S_TOK + s] = sc;
      atomicAdd(&hist1[__float_as_uint(sc) >> 16], 1u);
    }
  }
}

// ---------------- scan hi-16 histogram, find bin containing rank k ----------------
__global__ __launch_bounds__(1024) void scan_hi_kernel(const unsigned* __restrict__ hist,
                                                       unsigned* __restrict__ meta)
{
  const int t = threadIdx.x;
  unsigned v[64];
  unsigned s = 0;
  const uint4* hp = (const uint4*)(hist + t * 64);
#pragma unroll
  for (int i = 0; i < 16; i++) {
    uint4 q = hp[i];
    v[4*i+0] = q.x; v[4*i+1] = q.y; v[4*i+2] = q.z; v[4*i+3] = q.w;
    s += q.x + q.y + q.z + q.w;
  }
  __shared__ unsigned csum[1024];
  csum[t] = s;
  __syncthreads();
  for (int off = 1; off < 1024; off <<= 1) {
    unsigned add = (t + off < 1024) ? csum[t + off] : 0u;
    __syncthreads();
    csum[t] += add;
    __syncthreads();
  }
  const unsigned above = csum[t] - s;
  unsigned wacc = above;
  for (int i = 63; i >= 0; i--) {
    if (wacc < K_SEL && wacc + v[i] >= K_SEL) { meta[0] = (unsigned)(t * 64 + i); meta[1] = wacc; }
    wacc += v[i];
  }
}

// ---------------- lo-16 histogram of elements in the boundary hi-bin ----------------
__global__ __launch_bounds__(256) void hist2_kernel(const float* __restrict__ scores,
                                                    const unsigned* __restrict__ meta,
                                                    unsigned* __restrict__ hist2)
{
  unsigned i = blockIdx.x * 256 + threadIdx.x;
  unsigned b = __float_as_uint(scores[i]);
  if ((b >> 16) == meta[0]) atomicAdd(&hist2[b & 0xFFFFu], 1u);
}

__global__ __launch_bounds__(1024) void scan_lo_kernel(const unsigned* __restrict__ hist,
                                                       unsigned* __restrict__ meta)
{
  const unsigned base = meta[1];
  const unsigned bhi = meta[0];
  const int t = threadIdx.x;
  unsigned v[64];
  unsigned s = 0;
  const uint4* hp = (const uint4*)(hist + t * 64);
#pragma unroll
  for (int i = 0; i < 16; i++) {
    uint4 q = hp[i];
    v[4*i+0] = q.x; v[4*i+1] = q.y; v[4*i+2] = q.z; v[4*i+3] = q.w;
    s += q.x + q.y + q.z + q.w;
  }
  __shared__ unsigned csum[1024];
  csum[t] = s;
  __syncthreads();
  for (int off = 1; off < 1024; off <<= 1) {
    unsigned add = (t + off < 1024) ? csum[t + off] : 0u;
    __syncthreads();
    csum[t] += add;
    __syncthreads();
  }
  const unsigned above = csum[t] - s + base;
  unsigned wacc = above;
  for (int i = 63; i >= 0; i--) {
    if (wacc < K_SEL && wacc + v[i] >= K_SEL) {
      meta[2] = (bhi << 16) | (unsigned)(t * 64 + i);
      meta[3] = wacc;
      meta[4] = K_SEL - wacc;
    }
    wacc += v[i];
  }
}

// ---------------- selection: strict-greater appended, ties collected ----------------
__global__ __launch_bounds__(256) void sel_kernel(const float* __restrict__ scores,
                                                  unsigned* __restrict__ meta,
                                                  unsigned* __restrict__ counts,
                                                  int* __restrict__ tok_list,
                                                  float* __restrict__ coef_list,
                                                  unsigned* __restrict__ tie_idx)
{
  __shared__ unsigned lcnt[E_EXP], lbase[E_EXP];
  const int tid = threadIdx.x;
  if (tid < E_EXP) lcnt[tid] = 0;
  __syncthreads();
  const unsigned i = blockIdx.x * 256 + tid;
  const float v = scores[i];
  const unsigned b = __float_as_uint(v);
  const unsigned t = meta[2];
  const bool sel = (b > t);
  const unsigned e = i >> 14;
  unsigned myslot = 0;
  if (sel) myslot = atomicAdd(&lcnt[e], 1u);
  else if (b == t) {
    unsigned ts = atomicAdd(&meta[5], 1u);
    if (ts < 8192u) tie_idx[ts] = i;
  }
  __syncthreads();
  if (tid < E_EXP) lbase[tid] = atomicAdd(&counts[tid], lcnt[tid]);
  __syncthreads();
  if (sel) {
    unsigned p = e * S_TOK + lbase[e] + myslot;
    tok_list[p] = (int)(i & 16383u);
    coef_list[p] = v;
  }
}

// ---------------- tie resolution (lowest flat index first) ----------------
__global__ __launch_bounds__(256) void fin_kernel(const unsigned* __restrict__ meta,
                                                  const unsigned* __restrict__ tie_idx,
                                                  unsigned* __restrict__ counts,
                                                  int* __restrict__ tok_list,
                                                  float* __restrict__ coef_list)
{
  unsigned tcnt = meta[5]; if (tcnt > 8192u) tcnt = 8192u;
  const unsigned q = meta[4];
  const float tval = __uint_as_float(meta[2]);
  for (unsigned t = threadIdx.x; t < tcnt; t += 256) {
    unsigned idx = tie_idx[t];
    unsigned rank = 0;
    for (unsigned u = 0; u < tcnt; u++) rank += (tie_idx[u] < idx) ? 1u : 0u;
    if (rank < q) {
      unsigned e = idx >> 14;
      unsigned slot = atomicAdd(&counts[e], 1u);
      tok_list[e * S_TOK + slot] = (int)(idx & 16383u);
      coef_list[e * S_TOK + slot] = tval;
    }
  }
}

// ---------------- prefix offsets + tail outputs ----------------
__global__ void tail_kernel(const unsigned* __restrict__ counts, unsigned* __restrict__ exoff,
                            float* __restrict__ tail)
{
  if (threadIdx.x == 0) {
    unsigned o = 0;
    for (int e = 0; e < E_EXP; e++) { exoff[e] = o; o += counts[e]; }
    exoff[E_EXP] = o;
  }
  if (threadIdx.x < E_EXP) {
    tail[threadIdx.x] = (float)counts[threadIdx.x] * (1.0f / (float)K_SEL);
    tail[E_EXP + threadIdx.x] = 1.0f;
  }
}

// ---------------- GEMM1: H = gelu(Xg @ W1 + b1) -> bf16 hbuf ----------------
__global__ __launch_bounds__(256) void gemm1_kernel(
    const __hip_bfloat16* __restrict__ xb,      // [S][D]
    const __hip_bfloat16* __restrict__ w1t,     // [E][H][D]
    const float* __restrict__ b1,               // [E][H]
    const int* __restrict__ tok_list,           // [E][S]
    const unsigned* __restrict__ counts,
    const unsigned* __restrict__ exoff,
    __hip_bfloat16* __restrict__ hbuf)          // [K_SEL][H]
{
  const int e = blockIdx.z;
  const int cnt = (int)counts[e];
  const int m0 = blockIdx.y * 128;
  if (m0 >= cnt) return;
  const int n0 = blockIdx.x * 128;

  __shared__ __hip_bfloat16 As[128 * 32];
  __shared__ __hip_bfloat16 Bs[128 * 32];
  __shared__ int s_tok[128];

  const int tid = threadIdx.x;
  const int lane = tid & 63, w = tid >> 6;

  if (tid < 128) {
    int mi = m0 + tid;
    s_tok[tid] = tok_list[e * S_TOK + (mi < cnt ? mi : 0)];
  }
  __syncthreads();

  const int r0 = tid >> 2;
  const int cc8 = (tid & 3) * 8;
  const int r1 = r0 + 64;
  const size_t t0 = (size_t)s_tok[r0];
  const size_t t1 = (size_t)s_tok[r1];
  const __hip_bfloat16* a0 = xb + t0 * DDIM + cc8;
  const __hip_bfloat16* a1 = xb + t1 * DDIM + cc8;
  const __hip_bfloat16* w1e = w1t + (size_t)e * HDIM * DDIM;
  const __hip_bfloat16* bsrc0 = w1e + (size_t)(n0 + r0) * DDIM + cc8;
  const __hip_bfloat16* bsrc1 = w1e + (size_t)(n0 + r1) * DDIM + cc8;
  char* aldsb = (char*)As;
  char* bldsb = (char*)Bs;
  void* ad0 = aldsb + (w * 64) * 16;
  void* ad1 = aldsb + (256 + w * 64) * 16;
  void* bd0 = bldsb + (w * 64) * 16;
  void* bd1 = bldsb + (256 + w * 64) * 16;

  f32x4 acc[4][4] = {};
  const int wr = (w >> 1) * 64, wc = (w & 1) * 64;
  const int lr = lane & 15;
  const int kq = (lane >> 4) * 8;

  for (int k0 = 0; k0 < DDIM; k0 += 32) {
    __syncthreads();
    gload_lds16(a0 + k0, ad0);
    gload_lds16(a1 + k0, ad1);
    gload_lds16(bsrc0 + k0, bd0);
    gload_lds16(bsrc1 + k0, bd1);
    __syncthreads();
    bf16x8 af[4], bfr[4];
#pragma unroll
    for (int i = 0; i < 4; i++) af[i] = *(const bf16x8*)&As[(wr + i * 16 + lr) * 32 + kq];
#pragma unroll
    for (int j = 0; j < 4; j++) bfr[j] = *(const bf16x8*)&Bs[(wc + j * 16 + lr) * 32 + kq];
#pragma unroll
    for (int i = 0; i < 4; i++)
#pragma unroll
      for (int j = 0; j < 4; j++)
        acc[i][j] = __builtin_amdgcn_mfma_f32_16x16x32_bf16(af[i], bfr[j], acc[i][j], 0, 0, 0);
  }

  const int pbase = (int)exoff[e] + m0;
  const float* b1e = b1 + (size_t)e * HDIM;
#pragma unroll
  for (int j = 0; j < 4; j++) {
    const int n = n0 + wc + j * 16 + lr;
    const float bv = b1e[n];
#pragma unroll
    for (int i = 0; i < 4; i++) {
      const int mb = wr + i * 16 + (lane >> 4) * 4;
#pragma unroll
      for (int r = 0; r < 4; r++) {
        const int m = mb + r;
        if (m0 + m < cnt) {
          float vv = acc[i][j][r] + bv;
          hbuf[(size_t)(pbase + m) * HDIM + n] = __float2bfloat16(gelu_f(vv));
        }
      }
    }
  }
}

// ---------------- GEMM2: out += C * (H @ W2 + b2) ----------------
__global__ __launch_bounds__(256) void gemm2_kernel(
    const __hip_bfloat16* __restrict__ hbuf,    // [K_SEL][H]
    const __hip_bfloat16* __restrict__ w2t,     // [E][D][H]
    const float* __restrict__ b2,               // [E][D]
    const int* __restrict__ tok_list,
    const float* __restrict__ coef_list,
    const unsigned* __restrict__ counts,
    const unsigned* __restrict__ exoff,
    float* __restrict__ out)                    // [S][D]
{
  const int e = blockIdx.z;
  const int cnt = (int)counts[e];
  const int m0 = blockIdx.y * 128;
  if (m0 >= cnt) return;
  const int n0 = blockIdx.x * 128;

  __shared__ __hip_bfloat16 As[128 * 32];
  __shared__ __hip_bfloat16 Bs[128 * 32];
  __shared__ int s_tok[128];
  __shared__ float s_coef[128];

  const int tid = threadIdx.x;
  const int lane = tid & 63, w = tid >> 6;

  if (tid < 128) {
    int mi = m0 + tid;
    int cl = (mi < cnt) ? mi : 0;
    s_tok[tid] = tok_list[e * S_TOK + cl];
    s_coef[tid] = (mi < cnt) ? coef_list[e * S_TOK + mi] : 0.0f;
  }
  __syncthreads();

  const int r0 = tid >> 2;
  const int cc8 = (tid & 3) * 8;
  const int r1 = r0 + 64;
  const int pb = (int)exoff[e];
  const int p0 = pb + ((m0 + r0 < cnt) ? (m0 + r0) : 0);
  const int p1 = pb + ((m0 + r1 < cnt) ? (m0 + r1) : 0);
  const __hip_bfloat16* a0 = hbuf + (size_t)p0 * HDIM + cc8;
  const __hip_bfloat16* a1 = hbuf + (size_t)p1 * HDIM + cc8;
  const __hip_bfloat16* w2e = w2t + (size_t)e * DDIM * HDIM;
  const __hip_bfloat16* bsrc0 = w2e + (size_t)(n0 + r0) * HDIM + cc8;
  const __hip_bfloat16* bsrc1 = w2e + (size_t)(n0 + r1) * HDIM + cc8;
  char* aldsb = (char*)As;
  char* bldsb = (char*)Bs;
  void* ad0 = aldsb + (w * 64) * 16;
  void* ad1 = aldsb + (256 + w * 64) * 16;
  void* bd0 = bldsb + (w * 64) * 16;
  void* bd1 = bldsb + (256 + w * 64) * 16;

  f32x4 acc[4][4] = {};
  const int wr = (w >> 1) * 64, wc = (w & 1) * 64;
  const int lr = lane & 15;
  const int kq = (lane >> 4) * 8;

  for (int k0 = 0; k0 < HDIM; k0 += 32) {
    __syncthreads();
    gload_lds16(a0 + k0, ad0);
    gload_lds16(a1 + k0, ad1);
    gload_lds16(bsrc0 + k0, bd0);
    gload_lds16(bsrc1 + k0, bd1);
    __syncthreads();
    bf16x8 af[4], bfr[4];
#pragma unroll
    for (int i = 0; i < 4; i++) af[i] = *(const bf16x8*)&As[(wr + i * 16 + lr) * 32 + kq];
#pragma unroll
    for (int j = 0; j < 4; j++) bfr[j] = *(const bf16x8*)&Bs[(wc + j * 16 + lr) * 32 + kq];
#pragma unroll
    for (int i = 0; i < 4; i++)
#pragma unroll
      for (int j = 0; j < 4; j++)
        acc[i][j] = __builtin_amdgcn_mfma_f32_16x16x32_bf16(af[i], bfr[j], acc[i][j], 0, 0, 0);
  }

  const float* b2e = b2 + (size_t)e * DDIM;
#pragma unroll
  for (int j = 0; j < 4; j++) {
    const int n = n0 + wc + j * 16 + lr;
    const float bv = b2e[n];
#pragma unroll
    for (int i = 0; i < 4; i++) {
      const int mb = wr + i * 16 + (lane >> 4) * 4;
#pragma unroll
      for (int r = 0; r < 4; r++) {
        const int m = mb + r;
        if (m0 + m < cnt) {
          float y = acc[i][j][r] + bv;
          unsafeAtomicAdd(&out[(size_t)s_tok[m] * DDIM + n], s_coef[m] * y);
        }
      }
    }
  }
}

// ---------------- launch ----------------
extern "C" void kernel_launch(void* const* d_in, const int* in_sizes, int n_in,
                              void* d_out, int out_size, void* d_ws, size_t ws_size,
                              hipStream_t stream) {
  const float* x    = (const float*)d_in[0];
  const float* gw   = (const float*)d_in[1];
  const float* bias = (const float*)d_in[2];
  const float* W1   = (const float*)d_in[3];
  const float* b1   = (const float*)d_in[4];
  const float* W2   = (const float*)d_in[5];
  const float* b2   = (const float*)d_in[6];
  float* out = (float*)d_out;
  char* ws = (char*)d_ws;

  if (ws_size < (size_t)WS_TOTAL) {
    fprintf(stderr, "kernel_launch: ws_size %zu < required %u\n", ws_size, WS_TOTAL);
    return;
  }

  unsigned* hist1  = (unsigned*)(ws + WS_HIST1);
  unsigned* hist2  = (unsigned*)(ws + WS_HIST2);
  unsigned* meta   = (unsigned*)(ws + WS_META);
  unsigned* counts = (unsigned*)(ws + WS_COUNTS);
  unsigned* exoff  = (unsigned*)(ws + WS_EXOFF);
  unsigned* tiei   = (unsigned*)(ws + WS_TIEIDX);
  int*      tokl   = (int*)(ws + WS_TOK);
  float*    coefl  = (float*)(ws + WS_COEF);
  float*    scores = (float*)(ws + WS_SCORES);
  __hip_bfloat16* xb   = (__hip_bfloat16*)(ws + WS_XB);
  __hip_bfloat16* w1t  = (__hip_bfloat16*)(ws + WS_W1T);
  __hip_bfloat16* w2t  = (__hip_bfloat16*)(ws + WS_W2T);
  __hip_bfloat16* hbuf = (__hip_bfloat16*)(ws + WS_HBUF);

  hipMemsetAsync(ws, 0, WS_CLEAR, stream);
  hipMemsetAsync(out, 0, (size_t)out_size * sizeof(float), stream);

  // weight convert+transpose: W1 [E][D][H] -> [E][H][D]; W2 [E][H][D] -> [E][D][H]
  transpose_bf16_kernel<<<dim3(HDIM / 32, DDIM / 32, E_EXP), dim3(32, 8), 0, stream>>>(W1, w1t, DDIM, HDIM);
  transpose_bf16_kernel<<<dim3(DDIM / 32, HDIM / 32, E_EXP), dim3(32, 8), 0, stream>>>(W2, w2t, HDIM, DDIM);

  router_kernel<<<S_TOK / 4, 256, 0, stream>>>(x, gw, bias, scores, xb, hist1);
  scan_hi_kernel<<<1, 1024, 0, stream>>>(hist1, meta);
  hist2_kernel<<<ES / 256, 256, 0, stream>>>(scores, meta, hist2);
  scan_lo_kernel<<<1, 1024, 0, stream>>>(hist2, meta);
  sel_kernel<<<ES / 256, 256, 0, stream>>>(scores, meta, counts, tokl, coefl, tiei);
  fin_kernel<<<1, 256, 0, stream>>>(meta, tiei, counts, tokl, coefl);
  tail_kernel<<<1, 64, 0, stream>>>(counts, exoff, out + OUT_XO);

  gemm1_kernel<<<dim3(HDIM / 128, S_TOK / 128, E_EXP), 256, 0, stream>>>(
      xb, w1t, b1, tokl, counts, exoff, hbuf);
  gemm2_kernel<<<dim3(DDIM / 128, S_TOK / 128, E_EXP), 256, 0, stream>>>(
      hbuf, w2t, b2, tokl, coefl, counts, exoff, out);
}

// Round 2
// 1218.331 us; speedup vs baseline: 1.6932x; 1.6932x over previous
//
#include <hip/hip_runtime.h>
#include <hip/hip_bf16.h>
#include <cstdint>
#include <cstdio>
#include <math.h>

// ---------------- problem constants ----------------
#define S_TOK 16384     // B*SEQ
#define E_EXP 8
#define DDIM  1024
#define HDIM  4096
#define K_SEL 32768     // int(S * 2.0)
#define ES    131072    // E * S
#define OUT_XO 16777216 // S*D

// ---------------- workspace layout (bytes) ----------------
// meta: [0]=prefix (radix progress) [1]=count_above [2]=t_bits [3]=unused
//       [4]=need(ties to take) [5]=tie_cnt
#define WS_META    0x000000u   // 16 u32
#define WS_HIST    0x000100u   // 4 passes x 256 u32
#define WS_COUNTS  0x001100u   // 8 u32
#define WS_EXOFF   0x001200u   // 9 u32
#define WS_TIEIDX  0x001300u   // 8192 u32 (32KB)
#define WS_CLEAR   0x00A000u   // clear everything below this each launch
#define WS_TOK     0x010000u   // E*S int
#define WS_COEF    0x090000u   // E*S float
#define WS_SCORES  0x110000u   // E*S float
#define WS_XB      0x400000u   // S*D bf16 (32MB)
#define WS_W1T    0x2400000u   // E*H*D bf16 (64MB)
#define WS_W2T    0x6400000u   // E*D*H bf16 (64MB)
#define WS_HBUF   0xA400000u   // K_SEL*H bf16 (256MB)
#define WS_TOTAL  0x1A400000u  // ~420MB

typedef __attribute__((ext_vector_type(4))) float f32x4;
typedef __attribute__((ext_vector_type(8))) short bf16x8;

__device__ __forceinline__ void gload_lds16(const void* g, void* l) {
  __builtin_amdgcn_global_load_lds((const __attribute__((address_space(1))) void*)g,
                                   (__attribute__((address_space(3))) void*)l, 16, 0, 0);
}

__device__ __forceinline__ float gelu_f(float x) {
  float x3 = x * x * x;
  float u = 0.7978845608028654f * (x + 0.044715f * x3);
  return 0.5f * x * (1.0f + tanhf(u));
}

// ---------------- weight transpose + fp32->bf16 ----------------
// in: [E][R][C] fp32 ; out: [E][C][R] bf16
__global__ __launch_bounds__(256) void transpose_bf16_kernel(
    const float* __restrict__ in, __hip_bfloat16* __restrict__ outp, int R, int C)
{
  __shared__ float tile[32][33];
  const int c0 = blockIdx.x * 32, r0 = blockIdx.y * 32;
  const size_t eoff = (size_t)blockIdx.z * (size_t)R * (size_t)C;
  const float* ip = in + eoff;
  __hip_bfloat16* op = outp + eoff;
  const int tx = threadIdx.x, ty = threadIdx.y;
#pragma unroll
  for (int i = 0; i < 4; i++) {
    int r = ty + i * 8;
    tile[r][tx] = ip[(size_t)(r0 + r) * C + c0 + tx];
  }
  __syncthreads();
#pragma unroll
  for (int i = 0; i < 4; i++) {
    int c = ty + i * 8;
    op[(size_t)(c0 + c) * R + r0 + tx] = __float2bfloat16(tile[tx][c]);
  }
}

// ---------------- router: scores + x->bf16 (NO histogram here) ----------------
__global__ __launch_bounds__(256) void router_kernel(
    const float* __restrict__ x, const float* __restrict__ gw, const float* __restrict__ bias,
    float* __restrict__ scores, __hip_bfloat16* __restrict__ xb)
{
  __shared__ float g[E_EXP * DDIM];
  __shared__ float bs[E_EXP];
  const int tid = threadIdx.x;
  for (int i = tid; i < E_EXP * DDIM; i += 256) g[i] = gw[i];
  if (tid < E_EXP) bs[tid] = bias[tid];
  __syncthreads();
  const int w = tid >> 6, lane = tid & 63;
  const int s = blockIdx.x * 4 + w;
  double acc[E_EXP] = {0, 0, 0, 0, 0, 0, 0, 0};
  const float* xrow = x + (size_t)s * DDIM;
  __hip_bfloat16* xbrow = xb + (size_t)s * DDIM;
#pragma unroll 4
  for (int j = 0; j < 16; j++) {
    int d = lane + 64 * j;
    float xv = xrow[d];
    xbrow[d] = __float2bfloat16(xv);
#pragma unroll
    for (int e = 0; e < E_EXP; e++) acc[e] += (double)xv * (double)g[e * DDIM + d];
  }
#pragma unroll
  for (int e = 0; e < E_EXP; e++) {
    double a = acc[e];
#pragma unroll
    for (int off = 32; off > 0; off >>= 1) a += __shfl_xor(a, off);
    acc[e] = a;
  }
  if (lane == 0) {
#pragma unroll
    for (int e = 0; e < E_EXP; e++) {
      double lg = acc[e] + (double)bs[e];
      float sc = (float)(1.0 / (1.0 + exp(-lg)));
      scores[(size_t)e * S_TOK + s] = sc;
    }
  }
}

// ---------------- radix-8 select: histogram pass (LDS-aggregated) ----------------
// pass p: bin = (bits >> (24-8p)) & 0xFF, counted only if bits>>(32-8p) == prefix
__global__ __launch_bounds__(256) void hist_pass_kernel(
    const float* __restrict__ scores, const unsigned* __restrict__ meta,
    unsigned* __restrict__ hist, int pass)
{
  __shared__ unsigned h[256];
  const int tid = threadIdx.x;
  h[tid] = 0;
  __syncthreads();
  const unsigned prefix = meta[0];
  const int pshift = 32 - 8 * pass;     // 32,24,16,8
  const int bshift = 24 - 8 * pass;     // 24,16,8,0
  const unsigned base = blockIdx.x * 2048 + tid;
#pragma unroll
  for (int i = 0; i < 8; i++) {
    unsigned b = __float_as_uint(scores[base + i * 256]);
    bool ok = (pass == 0) || ((b >> pshift) == prefix);
    if (ok) atomicAdd(&h[(b >> bshift) & 0xFFu], 1u);
  }
  __syncthreads();
  if (h[tid]) atomicAdd(&hist[tid], h[tid]);
}

// ---------------- radix-8 select: scan pass (find boundary bin) ----------------
__global__ __launch_bounds__(256) void scan_pass_kernel(
    const unsigned* __restrict__ hist, unsigned* __restrict__ meta, int final)
{
  const int t = threadIdx.x;
  const unsigned v = hist[t];
  const unsigned prefix = meta[0];
  const unsigned above = meta[1];
  __shared__ unsigned csum[256];
  csum[t] = v;
  __syncthreads();
  for (int off = 1; off < 256; off <<= 1) {
    unsigned add = (t + off < 256) ? csum[t + off] : 0u;
    __syncthreads();
    csum[t] += add;
    __syncthreads();
  }
  const unsigned cge = csum[t];        // count with bin >= t (matching prefix)
  const unsigned cgt = cge - v;        // strictly greater bins
  if (above + cgt < K_SEL && above + cge >= K_SEL) {
    meta[0] = (prefix << 8) | (unsigned)t;
    meta[1] = above + cgt;
    if (final) {
      meta[2] = (prefix << 8) | (unsigned)t;  // exact 32-bit threshold
      meta[4] = K_SEL - (above + cgt);        // how many ties to take
    }
  }
}

// ---------------- selection: strict-greater appended, ties collected ----------------
__global__ __launch_bounds__(256) void sel_kernel(const float* __restrict__ scores,
                                                  unsigned* __restrict__ meta,
                                                  unsigned* __restrict__ counts,
                                                  int* __restrict__ tok_list,
                                                  float* __restrict__ coef_list,
                                                  unsigned* __restrict__ tie_idx)
{
  __shared__ unsigned lcnt[E_EXP], lbase[E_EXP];
  const int tid = threadIdx.x;
  if (tid < E_EXP) lcnt[tid] = 0;
  __syncthreads();
  const unsigned i = blockIdx.x * 256 + tid;
  const float v = scores[i];
  const unsigned b = __float_as_uint(v);
  const unsigned t = meta[2];
  const bool sel = (b > t);
  const unsigned e = i >> 14;
  unsigned myslot = 0;
  if (sel) myslot = atomicAdd(&lcnt[e], 1u);
  else if (b == t) {
    unsigned ts = atomicAdd(&meta[5], 1u);
    if (ts < 8192u) tie_idx[ts] = i;
  }
  __syncthreads();
  if (tid < E_EXP) lbase[tid] = atomicAdd(&counts[tid], lcnt[tid]);
  __syncthreads();
  if (sel) {
    unsigned p = e * S_TOK + lbase[e] + myslot;
    tok_list[p] = (int)(i & 16383u);
    coef_list[p] = v;
  }
}

// ---------------- tie resolution (lowest flat index first) ----------------
__global__ __launch_bounds__(256) void fin_kernel(const unsigned* __restrict__ meta,
                                                  const unsigned* __restrict__ tie_idx,
                                                  unsigned* __restrict__ counts,
                                                  int* __restrict__ tok_list,
                                                  float* __restrict__ coef_list)
{
  unsigned tcnt = meta[5]; if (tcnt > 8192u) tcnt = 8192u;
  const unsigned q = meta[4];
  const float tval = __uint_as_float(meta[2]);
  for (unsigned t = threadIdx.x; t < tcnt; t += 256) {
    unsigned idx = tie_idx[t];
    unsigned rank = 0;
    for (unsigned u = 0; u < tcnt; u++) rank += (tie_idx[u] < idx) ? 1u : 0u;
    if (rank < q) {
      unsigned e = idx >> 14;
      unsigned slot = atomicAdd(&counts[e], 1u);
      tok_list[e * S_TOK + slot] = (int)(idx & 16383u);
      coef_list[e * S_TOK + slot] = tval;
    }
  }
}

// ---------------- prefix offsets + tail outputs ----------------
__global__ void tail_kernel(const unsigned* __restrict__ counts, unsigned* __restrict__ exoff,
                            float* __restrict__ tail)
{
  if (threadIdx.x == 0) {
    unsigned o = 0;
    for (int e = 0; e < E_EXP; e++) { exoff[e] = o; o += counts[e]; }
    exoff[E_EXP] = o;
  }
  if (threadIdx.x < E_EXP) {
    tail[threadIdx.x] = (float)counts[threadIdx.x] * (1.0f / (float)K_SEL);
    tail[E_EXP + threadIdx.x] = 1.0f;
  }
}

// ---------------- GEMM1: H = gelu(Xg @ W1 + b1) -> bf16 hbuf ----------------
__global__ __launch_bounds__(256) void gemm1_kernel(
    const __hip_bfloat16* __restrict__ xb,      // [S][D]
    const __hip_bfloat16* __restrict__ w1t,     // [E][H][D]
    const float* __restrict__ b1,               // [E][H]
    const int* __restrict__ tok_list,           // [E][S]
    const unsigned* __restrict__ counts,
    const unsigned* __restrict__ exoff,
    __hip_bfloat16* __restrict__ hbuf)          // [K_SEL][H]
{
  const int e = blockIdx.z;
  const int cnt = (int)counts[e];
  const int m0 = blockIdx.y * 128;
  if (m0 >= cnt) return;
  const int n0 = blockIdx.x * 128;

  __shared__ __hip_bfloat16 As[128 * 32];
  __shared__ __hip_bfloat16 Bs[128 * 32];
  __shared__ int s_tok[128];

  const int tid = threadIdx.x;
  const int lane = tid & 63, w = tid >> 6;

  if (tid < 128) {
    int mi = m0 + tid;
    s_tok[tid] = tok_list[e * S_TOK + (mi < cnt ? mi : 0)];
  }
  __syncthreads();

  const int r0 = tid >> 2;
  const int cc8 = (tid & 3) * 8;
  const int r1 = r0 + 64;
  const size_t t0 = (size_t)s_tok[r0];
  const size_t t1 = (size_t)s_tok[r1];
  const __hip_bfloat16* a0 = xb + t0 * DDIM + cc8;
  const __hip_bfloat16* a1 = xb + t1 * DDIM + cc8;
  const __hip_bfloat16* w1e = w1t + (size_t)e * HDIM * DDIM;
  const __hip_bfloat16* bsrc0 = w1e + (size_t)(n0 + r0) * DDIM + cc8;
  const __hip_bfloat16* bsrc1 = w1e + (size_t)(n0 + r1) * DDIM + cc8;
  char* aldsb = (char*)As;
  char* bldsb = (char*)Bs;
  void* ad0 = aldsb + (w * 64) * 16;
  void* ad1 = aldsb + (256 + w * 64) * 16;
  void* bd0 = bldsb + (w * 64) * 16;
  void* bd1 = bldsb + (256 + w * 64) * 16;

  f32x4 acc[4][4] = {};
  const int wr = (w >> 1) * 64, wc = (w & 1) * 64;
  const int lr = lane & 15;
  const int kq = (lane >> 4) * 8;

  for (int k0 = 0; k0 < DDIM; k0 += 32) {
    __syncthreads();
    gload_lds16(a0 + k0, ad0);
    gload_lds16(a1 + k0, ad1);
    gload_lds16(bsrc0 + k0, bd0);
    gload_lds16(bsrc1 + k0, bd1);
    __syncthreads();
    bf16x8 af[4], bfr[4];
#pragma unroll
    for (int i = 0; i < 4; i++) af[i] = *(const bf16x8*)&As[(wr + i * 16 + lr) * 32 + kq];
#pragma unroll
    for (int j = 0; j < 4; j++) bfr[j] = *(const bf16x8*)&Bs[(wc + j * 16 + lr) * 32 + kq];
#pragma unroll
    for (int i = 0; i < 4; i++)
#pragma unroll
      for (int j = 0; j < 4; j++)
        acc[i][j] = __builtin_amdgcn_mfma_f32_16x16x32_bf16(af[i], bfr[j], acc[i][j], 0, 0, 0);
  }

  const int pbase = (int)exoff[e] + m0;
  const float* b1e = b1 + (size_t)e * HDIM;
#pragma unroll
  for (int j = 0; j < 4; j++) {
    const int n = n0 + wc + j * 16 + lr;
    const float bv = b1e[n];
#pragma unroll
    for (int i = 0; i < 4; i++) {
      const int mb = wr + i * 16 + (lane >> 4) * 4;
#pragma unroll
      for (int r = 0; r < 4; r++) {
        const int m = mb + r;
        if (m0 + m < cnt) {
          float vv = acc[i][j][r] + bv;
          hbuf[(size_t)(pbase + m) * HDIM + n] = __float2bfloat16(gelu_f(vv));
        }
      }
    }
  }
}

// ---------------- GEMM2: out += C * (H @ W2 + b2) ----------------
__global__ __launch_bounds__(256) void gemm2_kernel(
    const __hip_bfloat16* __restrict__ hbuf,    // [K_SEL][H]
    const __hip_bfloat16* __restrict__ w2t,     // [E][D][H]
    const float* __restrict__ b2,               // [E][D]
    const int* __restrict__ tok_list,
    const float* __restrict__ coef_list,
    const unsigned* __restrict__ counts,
    const unsigned* __restrict__ exoff,
    float* __restrict__ out)                    // [S][D]
{
  const int e = blockIdx.z;
  const int cnt = (int)counts[e];
  const int m0 = blockIdx.y * 128;
  if (m0 >= cnt) return;
  const int n0 = blockIdx.x * 128;

  __shared__ __hip_bfloat16 As[128 * 32];
  __shared__ __hip_bfloat16 Bs[128 * 32];
  __shared__ int s_tok[128];
  __shared__ float s_coef[128];

  const int tid = threadIdx.x;
  const int lane = tid & 63, w = tid >> 6;

  if (tid < 128) {
    int mi = m0 + tid;
    int cl = (mi < cnt) ? mi : 0;
    s_tok[tid] = tok_list[e * S_TOK + cl];
    s_coef[tid] = (mi < cnt) ? coef_list[e * S_TOK + mi] : 0.0f;
  }
  __syncthreads();

  const int r0 = tid >> 2;
  const int cc8 = (tid & 3) * 8;
  const int r1 = r0 + 64;
  const int pb = (int)exoff[e];
  const int p0 = pb + ((m0 + r0 < cnt) ? (m0 + r0) : 0);
  const int p1 = pb + ((m0 + r1 < cnt) ? (m0 + r1) : 0);
  const __hip_bfloat16* a0 = hbuf + (size_t)p0 * HDIM + cc8;
  const __hip_bfloat16* a1 = hbuf + (size_t)p1 * HDIM + cc8;
  const __hip_bfloat16* w2e = w2t + (size_t)e * DDIM * HDIM;
  const __hip_bfloat16* bsrc0 = w2e + (size_t)(n0 + r0) * HDIM + cc8;
  const __hip_bfloat16* bsrc1 = w2e + (size_t)(n0 + r1) * HDIM + cc8;
  char* aldsb = (char*)As;
  char* bldsb = (char*)Bs;
  void* ad0 = aldsb + (w * 64) * 16;
  void* ad1 = aldsb + (256 + w * 64) * 16;
  void* bd0 = bldsb + (w * 64) * 16;
  void* bd1 = bldsb + (256 + w * 64) * 16;

  f32x4 acc[4][4] = {};
  const int wr = (w >> 1) * 64, wc = (w & 1) * 64;
  const int lr = lane & 15;
  const int kq = (lane >> 4) * 8;

  for (int k0 = 0; k0 < HDIM; k0 += 32) {
    __syncthreads();
    gload_lds16(a0 + k0, ad0);
    gload_lds16(a1 + k0, ad1);
    gload_lds16(bsrc0 + k0, bd0);
    gload_lds16(bsrc1 + k0, bd1);
    __syncthreads();
    bf16x8 af[4], bfr[4];
#pragma unroll
    for (int i = 0; i < 4; i++) af[i] = *(const bf16x8*)&As[(wr + i * 16 + lr) * 32 + kq];
#pragma unroll
    for (int j = 0; j < 4; j++) bfr[j] = *(const bf16x8*)&Bs[(wc + j * 16 + lr) * 32 + kq];
#pragma unroll
    for (int i = 0; i < 4; i++)
#pragma unroll
      for (int j = 0; j < 4; j++)
        acc[i][j] = __builtin_amdgcn_mfma_f32_16x16x32_bf16(af[i], bfr[j], acc[i][j], 0, 0, 0);
  }

  const float* b2e = b2 + (size_t)e * DDIM;
#pragma unroll
  for (int j = 0; j < 4; j++) {
    const int n = n0 + wc + j * 16 + lr;
    const float bv = b2e[n];
#pragma unroll
    for (int i = 0; i < 4; i++) {
      const int mb = wr + i * 16 + (lane >> 4) * 4;
#pragma unroll
      for (int r = 0; r < 4; r++) {
        const int m = mb + r;
        if (m0 + m < cnt) {
          float y = acc[i][j][r] + bv;
          unsafeAtomicAdd(&out[(size_t)s_tok[m] * DDIM + n], s_coef[m] * y);
        }
      }
    }
  }
}

// ---------------- launch ----------------
extern "C" void kernel_launch(void* const* d_in, const int* in_sizes, int n_in,
                              void* d_out, int out_size, void* d_ws, size_t ws_size,
                              hipStream_t stream) {
  const float* x    = (const float*)d_in[0];
  const float* gw   = (const float*)d_in[1];
  const float* bias = (const float*)d_in[2];
  const float* W1   = (const float*)d_in[3];
  const float* b1   = (const float*)d_in[4];
  const float* W2   = (const float*)d_in[5];
  const float* b2   = (const float*)d_in[6];
  float* out = (float*)d_out;
  char* ws = (char*)d_ws;

  if (ws_size < (size_t)WS_TOTAL) {
    fprintf(stderr, "kernel_launch: ws_size %zu < required %u\n", ws_size, WS_TOTAL);
    return;
  }

  unsigned* meta   = (unsigned*)(ws + WS_META);
  unsigned* hist   = (unsigned*)(ws + WS_HIST);
  unsigned* counts = (unsigned*)(ws + WS_COUNTS);
  unsigned* exoff  = (unsigned*)(ws + WS_EXOFF);
  unsigned* tiei   = (unsigned*)(ws + WS_TIEIDX);
  int*      tokl   = (int*)(ws + WS_TOK);
  float*    coefl  = (float*)(ws + WS_COEF);
  float*    scores = (float*)(ws + WS_SCORES);
  __hip_bfloat16* xb   = (__hip_bfloat16*)(ws + WS_XB);
  __hip_bfloat16* w1t  = (__hip_bfloat16*)(ws + WS_W1T);
  __hip_bfloat16* w2t  = (__hip_bfloat16*)(ws + WS_W2T);
  __hip_bfloat16* hbuf = (__hip_bfloat16*)(ws + WS_HBUF);

  hipMemsetAsync(ws, 0, WS_CLEAR, stream);
  hipMemsetAsync(out, 0, (size_t)out_size * sizeof(float), stream);

  // weight convert+transpose: W1 [E][D][H] -> [E][H][D]; W2 [E][H][D] -> [E][D][H]
  transpose_bf16_kernel<<<dim3(HDIM / 32, DDIM / 32, E_EXP), dim3(32, 8), 0, stream>>>(W1, w1t, DDIM, HDIM);
  transpose_bf16_kernel<<<dim3(DDIM / 32, HDIM / 32, E_EXP), dim3(32, 8), 0, stream>>>(W2, w2t, HDIM, DDIM);

  router_kernel<<<S_TOK / 4, 256, 0, stream>>>(x, gw, bias, scores, xb);

  // exact global top-k via 4-pass radix-8 select
  for (int p = 0; p < 4; p++) {
    hist_pass_kernel<<<ES / 2048, 256, 0, stream>>>(scores, meta, hist + p * 256, p);
    scan_pass_kernel<<<1, 256, 0, stream>>>(hist + p * 256, meta, p == 3);
  }
  sel_kernel<<<ES / 256, 256, 0, stream>>>(scores, meta, counts, tokl, coefl, tiei);
  fin_kernel<<<1, 256, 0, stream>>>(meta, tiei, counts, tokl, coefl);
  tail_kernel<<<1, 64, 0, stream>>>(counts, exoff, out + OUT_XO);

  gemm1_kernel<<<dim3(HDIM / 128, S_TOK / 128, E_EXP), 256, 0, stream>>>(
      xb, w1t, b1, tokl, counts, exoff, hbuf);
  gemm2_kernel<<<dim3(DDIM / 128, S_TOK / 128, E_EXP), 256, 0, stream>>>(
      hbuf, w2t, b2, tokl, coefl, counts, exoff, out);
}

// Round 3
// 1082.513 us; speedup vs baseline: 1.9056x; 1.1255x over previous
//
#include <hip/hip_runtime.h>
#include <hip/hip_bf16.h>
#include <cstdint>
#include <cstdio>
#include <math.h>

// ---------------- problem constants ----------------
#define S_TOK 16384     // B*SEQ
#define E_EXP 8
#define DDIM  1024
#define HDIM  4096
#define K_SEL 32768     // int(S * 2.0)
#define ES    131072    // E * S
#define OUT_XO 16777216 // S*D

// ---------------- workspace layout (bytes) ----------------
// meta: [0]=prefix (radix progress) [1]=count_above [2]=t_bits [3]=unused
//       [4]=need(ties to take) [5]=tie_cnt
#define WS_META    0x000000u   // 16 u32
#define WS_HIST    0x000100u   // 4 passes x 256 u32
#define WS_COUNTS  0x001100u   // 8 u32
#define WS_EXOFF   0x001200u   // 9 u32
#define WS_TIEIDX  0x001300u   // 8192 u32 (32KB)
#define WS_CLEAR   0x00A000u   // clear everything below this each launch
#define WS_TOK     0x010000u   // E*S int
#define WS_COEF    0x090000u   // E*S float
#define WS_SCORES  0x110000u   // E*S float
#define WS_TCNT    0x190000u   // S u32 (64KB) -- zeroed separately
#define WS_TSLOT   0x1A0000u   // S*8 u32 (512KB)
#define WS_XB      0x400000u   // S*D bf16 (32MB)
#define WS_W1T    0x2400000u   // E*H*D bf16 (64MB)  [aliased as ybuf after gemm1]
#define WS_W2T    0x6400000u   // E*D*H bf16 (64MB)
#define WS_HBUF   0xA400000u   // K_SEL*H bf16 (256MB)
#define WS_TOTAL  0x1A400000u  // ~420MB
#define WS_YBUF   WS_W1T       // K_SEL*D bf16 (64MB) -- reuses W1T after gemm1 done

typedef __attribute__((ext_vector_type(4))) float f32x4;
typedef __attribute__((ext_vector_type(8))) short bf16x8;

__device__ __forceinline__ void gload_lds16(const void* g, void* l) {
  __builtin_amdgcn_global_load_lds((const __attribute__((address_space(1))) void*)g,
                                   (__attribute__((address_space(3))) void*)l, 16, 0, 0);
}

// gelu tanh-approx via sigmoid form: 0.5x(1+tanh(u)) = x * sigmoid(2u)
// sigmoid(2u) = 1/(1+exp(-2u)); exp(-2u)=exp2(-2u*log2e). c = 2*0.7978845608*1.4426950408
__device__ __forceinline__ float gelu_f(float x) {
  float u = __builtin_fmaf(x * x * x, 0.044715f, x);
  float e = __builtin_amdgcn_exp2f(-2.302207976f * u);
  return x * __builtin_amdgcn_rcpf(1.0f + e);
}

// ---------------- weight transpose + fp32->bf16 ----------------
// in: [E][R][C] fp32 ; out: [E][C][R] bf16
__global__ __launch_bounds__(256) void transpose_bf16_kernel(
    const float* __restrict__ in, __hip_bfloat16* __restrict__ outp, int R, int C)
{
  __shared__ float tile[32][33];
  const int c0 = blockIdx.x * 32, r0 = blockIdx.y * 32;
  const size_t eoff = (size_t)blockIdx.z * (size_t)R * (size_t)C;
  const float* ip = in + eoff;
  __hip_bfloat16* op = outp + eoff;
  const int tx = threadIdx.x, ty = threadIdx.y;
#pragma unroll
  for (int i = 0; i < 4; i++) {
    int r = ty + i * 8;
    tile[r][tx] = ip[(size_t)(r0 + r) * C + c0 + tx];
  }
  __syncthreads();
#pragma unroll
  for (int i = 0; i < 4; i++) {
    int c = ty + i * 8;
    op[(size_t)(c0 + c) * R + r0 + tx] = __float2bfloat16(tile[tx][c]);
  }
}

// ---------------- router: scores + x->bf16 ----------------
__global__ __launch_bounds__(256) void router_kernel(
    const float* __restrict__ x, const float* __restrict__ gw, const float* __restrict__ bias,
    float* __restrict__ scores, __hip_bfloat16* __restrict__ xb)
{
  __shared__ float g[E_EXP * DDIM];
  __shared__ float bs[E_EXP];
  const int tid = threadIdx.x;
  for (int i = tid; i < E_EXP * DDIM; i += 256) g[i] = gw[i];
  if (tid < E_EXP) bs[tid] = bias[tid];
  __syncthreads();
  const int w = tid >> 6, lane = tid & 63;
  const int s = blockIdx.x * 4 + w;
  double acc[E_EXP] = {0, 0, 0, 0, 0, 0, 0, 0};
  const float* xrow = x + (size_t)s * DDIM;
  __hip_bfloat16* xbrow = xb + (size_t)s * DDIM;
#pragma unroll 4
  for (int j = 0; j < 16; j++) {
    int d = lane + 64 * j;
    float xv = xrow[d];
    xbrow[d] = __float2bfloat16(xv);
#pragma unroll
    for (int e = 0; e < E_EXP; e++) acc[e] += (double)xv * (double)g[e * DDIM + d];
  }
#pragma unroll
  for (int e = 0; e < E_EXP; e++) {
    double a = acc[e];
#pragma unroll
    for (int off = 32; off > 0; off >>= 1) a += __shfl_xor(a, off);
    acc[e] = a;
  }
  if (lane == 0) {
#pragma unroll
    for (int e = 0; e < E_EXP; e++) {
      double lg = acc[e] + (double)bs[e];
      float sc = (float)(1.0 / (1.0 + exp(-lg)));
      scores[(size_t)e * S_TOK + s] = sc;
    }
  }
}

// ---------------- radix-8 select: histogram pass (LDS-aggregated) ----------------
__global__ __launch_bounds__(256) void hist_pass_kernel(
    const float* __restrict__ scores, const unsigned* __restrict__ meta,
    unsigned* __restrict__ hist, int pass)
{
  __shared__ unsigned h[256];
  const int tid = threadIdx.x;
  h[tid] = 0;
  __syncthreads();
  const unsigned prefix = meta[0];
  const int pshift = 32 - 8 * pass;     // 32,24,16,8
  const int bshift = 24 - 8 * pass;     // 24,16,8,0
  const unsigned base = blockIdx.x * 2048 + tid;
#pragma unroll
  for (int i = 0; i < 8; i++) {
    unsigned b = __float_as_uint(scores[base + i * 256]);
    bool ok = (pass == 0) || ((b >> pshift) == prefix);
    if (ok) atomicAdd(&h[(b >> bshift) & 0xFFu], 1u);
  }
  __syncthreads();
  if (h[tid]) atomicAdd(&hist[tid], h[tid]);
}

// ---------------- radix-8 select: scan pass (find boundary bin) ----------------
__global__ __launch_bounds__(256) void scan_pass_kernel(
    const unsigned* __restrict__ hist, unsigned* __restrict__ meta, int final)
{
  const int t = threadIdx.x;
  const unsigned v = hist[t];
  const unsigned prefix = meta[0];
  const unsigned above = meta[1];
  __shared__ unsigned csum[256];
  csum[t] = v;
  __syncthreads();
  for (int off = 1; off < 256; off <<= 1) {
    unsigned add = (t + off < 256) ? csum[t + off] : 0u;
    __syncthreads();
    csum[t] += add;
    __syncthreads();
  }
  const unsigned cge = csum[t];        // count with bin >= t (matching prefix)
  const unsigned cgt = cge - v;        // strictly greater bins
  if (above + cgt < K_SEL && above + cge >= K_SEL) {
    meta[0] = (prefix << 8) | (unsigned)t;
    meta[1] = above + cgt;
    if (final) {
      meta[2] = (prefix << 8) | (unsigned)t;  // exact 32-bit threshold
      meta[4] = K_SEL - (above + cgt);        // how many ties to take
    }
  }
}

// ---------------- selection: strict-greater appended, ties collected ----------------
__global__ __launch_bounds__(256) void sel_kernel(const float* __restrict__ scores,
                                                  unsigned* __restrict__ meta,
                                                  unsigned* __restrict__ counts,
                                                  int* __restrict__ tok_list,
                                                  float* __restrict__ coef_list,
                                                  unsigned* __restrict__ tie_idx,
                                                  unsigned* __restrict__ tcnt,
                                                  unsigned* __restrict__ tslot)
{
  __shared__ unsigned lcnt[E_EXP], lbase[E_EXP];
  const int tid = threadIdx.x;
  if (tid < E_EXP) lcnt[tid] = 0;
  __syncthreads();
  const unsigned i = blockIdx.x * 256 + tid;
  const float v = scores[i];
  const unsigned b = __float_as_uint(v);
  const unsigned t = meta[2];
  const bool sel = (b > t);
  const unsigned e = i >> 14;
  unsigned myslot = 0;
  if (sel) myslot = atomicAdd(&lcnt[e], 1u);
  else if (b == t) {
    unsigned ts = atomicAdd(&meta[5], 1u);
    if (ts < 8192u) tie_idx[ts] = i;
  }
  __syncthreads();
  if (tid < E_EXP) lbase[tid] = atomicAdd(&counts[tid], lcnt[tid]);
  __syncthreads();
  if (sel) {
    const unsigned slot = lbase[e] + myslot;
    const unsigned p = e * S_TOK + slot;
    const unsigned tok = i & 16383u;
    tok_list[p] = (int)tok;
    coef_list[p] = v;
    unsigned us = atomicAdd(&tcnt[tok], 1u);
    tslot[tok * 8u + us] = (e << 14) | slot;
  }
}

// ---------------- tie resolution (lowest flat index first) ----------------
__global__ __launch_bounds__(256) void fin_kernel(const unsigned* __restrict__ meta,
                                                  const unsigned* __restrict__ tie_idx,
                                                  unsigned* __restrict__ counts,
                                                  int* __restrict__ tok_list,
                                                  float* __restrict__ coef_list,
                                                  unsigned* __restrict__ tcnt,
                                                  unsigned* __restrict__ tslot)
{
  unsigned tcnt_ties = meta[5]; if (tcnt_ties > 8192u) tcnt_ties = 8192u;
  const unsigned q = meta[4];
  const float tval = __uint_as_float(meta[2]);
  for (unsigned t = threadIdx.x; t < tcnt_ties; t += 256) {
    unsigned idx = tie_idx[t];
    unsigned rank = 0;
    for (unsigned u = 0; u < tcnt_ties; u++) rank += (tie_idx[u] < idx) ? 1u : 0u;
    if (rank < q) {
      const unsigned e = idx >> 14;
      const unsigned tok = idx & 16383u;
      const unsigned slot = atomicAdd(&counts[e], 1u);
      tok_list[e * S_TOK + slot] = (int)tok;
      coef_list[e * S_TOK + slot] = tval;
      unsigned us = atomicAdd(&tcnt[tok], 1u);
      tslot[tok * 8u + us] = (e << 14) | slot;
    }
  }
}

// ---------------- prefix offsets + tail outputs ----------------
__global__ void tail_kernel(const unsigned* __restrict__ counts, unsigned* __restrict__ exoff,
                            float* __restrict__ tail)
{
  if (threadIdx.x == 0) {
    unsigned o = 0;
    for (int e = 0; e < E_EXP; e++) { exoff[e] = o; o += counts[e]; }
    exoff[E_EXP] = o;
  }
  if (threadIdx.x < E_EXP) {
    tail[threadIdx.x] = (float)counts[threadIdx.x] * (1.0f / (float)K_SEL);
    tail[E_EXP + threadIdx.x] = 1.0f;
  }
}

// ---------------- GEMM1: H = gelu(Xg @ W1 + b1) -> bf16 hbuf ----------------
__global__ __launch_bounds__(256) void gemm1_kernel(
    const __hip_bfloat16* __restrict__ xb,      // [S][D]
    const __hip_bfloat16* __restrict__ w1t,     // [E][H][D]
    const float* __restrict__ b1,               // [E][H]
    const int* __restrict__ tok_list,           // [E][S]
    const unsigned* __restrict__ counts,
    const unsigned* __restrict__ exoff,
    __hip_bfloat16* __restrict__ hbuf)          // [K_SEL][H]
{
  const int e = blockIdx.z;
  const int cnt = (int)counts[e];
  const int m0 = blockIdx.y * 128;
  if (m0 >= cnt) return;
  const int n0 = blockIdx.x * 128;

  // 17408B pool: As(8K)+Bs(8K) during K-loop; 64x136 bf16 stage tile in epilogue
  __shared__ __align__(16) char smem[17408];
  __hip_bfloat16* As = (__hip_bfloat16*)smem;
  __hip_bfloat16* Bs = (__hip_bfloat16*)(smem + 8192);
  __hip_bfloat16* stg = (__hip_bfloat16*)smem;
  __shared__ int s_tok[128];

  const int tid = threadIdx.x;
  const int lane = tid & 63, w = tid >> 6;

  if (tid < 128) {
    int mi = m0 + tid;
    s_tok[tid] = tok_list[e * S_TOK + (mi < cnt ? mi : 0)];
  }
  __syncthreads();

  const int r0 = tid >> 2;
  const int cc8 = (tid & 3) * 8;
  const int r1 = r0 + 64;
  const size_t t0 = (size_t)s_tok[r0];
  const size_t t1 = (size_t)s_tok[r1];
  const __hip_bfloat16* a0 = xb + t0 * DDIM + cc8;
  const __hip_bfloat16* a1 = xb + t1 * DDIM + cc8;
  const __hip_bfloat16* w1e = w1t + (size_t)e * HDIM * DDIM;
  const __hip_bfloat16* bsrc0 = w1e + (size_t)(n0 + r0) * DDIM + cc8;
  const __hip_bfloat16* bsrc1 = w1e + (size_t)(n0 + r1) * DDIM + cc8;
  void* ad0 = smem + (w * 64) * 16;
  void* ad1 = smem + (256 + w * 64) * 16;
  void* bd0 = smem + 8192 + (w * 64) * 16;
  void* bd1 = smem + 8192 + (256 + w * 64) * 16;

  f32x4 acc[4][4] = {};
  const int wr = (w >> 1) * 64, wc = (w & 1) * 64;
  const int lr = lane & 15;
  const int kq = (lane >> 4) * 8;

  for (int k0 = 0; k0 < DDIM; k0 += 32) {
    __syncthreads();
    gload_lds16(a0 + k0, ad0);
    gload_lds16(a1 + k0, ad1);
    gload_lds16(bsrc0 + k0, bd0);
    gload_lds16(bsrc1 + k0, bd1);
    __syncthreads();
    bf16x8 af[4], bfr[4];
#pragma unroll
    for (int i = 0; i < 4; i++) af[i] = *(const bf16x8*)&As[(wr + i * 16 + lr) * 32 + kq];
#pragma unroll
    for (int j = 0; j < 4; j++) bfr[j] = *(const bf16x8*)&Bs[(wc + j * 16 + lr) * 32 + kq];
#pragma unroll
    for (int i = 0; i < 4; i++)
#pragma unroll
      for (int j = 0; j < 4; j++)
        acc[i][j] = __builtin_amdgcn_mfma_f32_16x16x32_bf16(af[i], bfr[j], acc[i][j], 0, 0, 0);
  }

  // ---- epilogue: gelu + LDS repack -> coalesced dwordx4 stores ----
  const int pbase = (int)exoff[e] + m0;
  const float* b1e = b1 + (size_t)e * HDIM;
  float bvj[4];
#pragma unroll
  for (int j = 0; j < 4; j++) bvj[j] = b1e[n0 + wc + j * 16 + lr];

  const int rt = tid >> 2;           // row 0..63 within stage tile
  const int chb = (tid & 3) * 8;     // 16B chunk base col
#pragma unroll
  for (int P = 0; P < 2; P++) {
    __syncthreads();
    if ((w >> 1) == P) {
#pragma unroll
      for (int i = 0; i < 4; i++)
#pragma unroll
        for (int j = 0; j < 4; j++)
#pragma unroll
          for (int r = 0; r < 4; r++) {
            const int rrel = i * 16 + (lane >> 4) * 4 + r;
            const int col = wc + j * 16 + lr;
            stg[rrel * 136 + col] = __float2bfloat16(gelu_f(acc[i][j][r] + bvj[j]));
          }
    }
    __syncthreads();
    const int m = P * 64 + rt;
    if (m0 + m < cnt) {
      __hip_bfloat16* dst = hbuf + (size_t)(pbase + m) * HDIM + n0;
      const __hip_bfloat16* src = &stg[rt * 136];
#pragma unroll
      for (int c = 0; c < 4; c++)
        *(uint4*)(dst + chb + c * 32) = *(const uint4*)(src + chb + c * 32);
    }
  }
}

// ---------------- GEMM2: ybuf[slot] = coef * (H @ W2 + b2) -> bf16 ----------------
__global__ __launch_bounds__(256) void gemm2_kernel(
    const __hip_bfloat16* __restrict__ hbuf,    // [K_SEL][H]
    const __hip_bfloat16* __restrict__ w2t,     // [E][D][H]
    const float* __restrict__ b2,               // [E][D]
    const float* __restrict__ coef_list,
    const unsigned* __restrict__ counts,
    const unsigned* __restrict__ exoff,
    __hip_bfloat16* __restrict__ ybuf)          // [K_SEL][D]
{
  const int e = blockIdx.z;
  const int cnt = (int)counts[e];
  const int m0 = blockIdx.y * 128;
  if (m0 >= cnt) return;
  const int n0 = blockIdx.x * 128;

  __shared__ __align__(16) char smem[17408];
  __hip_bfloat16* As = (__hip_bfloat16*)smem;
  __hip_bfloat16* Bs = (__hip_bfloat16*)(smem + 8192);
  __hip_bfloat16* stg = (__hip_bfloat16*)smem;
  __shared__ float s_coef[128];

  const int tid = threadIdx.x;
  const int lane = tid & 63, w = tid >> 6;

  if (tid < 128) {
    int mi = m0 + tid;
    s_coef[tid] = (mi < cnt) ? coef_list[e * S_TOK + mi] : 0.0f;
  }
  __syncthreads();

  const int r0 = tid >> 2;
  const int cc8 = (tid & 3) * 8;
  const int r1 = r0 + 64;
  const int pb = (int)exoff[e];
  const int p0 = pb + ((m0 + r0 < cnt) ? (m0 + r0) : 0);
  const int p1 = pb + ((m0 + r1 < cnt) ? (m0 + r1) : 0);
  const __hip_bfloat16* a0 = hbuf + (size_t)p0 * HDIM + cc8;
  const __hip_bfloat16* a1 = hbuf + (size_t)p1 * HDIM + cc8;
  const __hip_bfloat16* w2e = w2t + (size_t)e * DDIM * HDIM;
  const __hip_bfloat16* bsrc0 = w2e + (size_t)(n0 + r0) * HDIM + cc8;
  const __hip_bfloat16* bsrc1 = w2e + (size_t)(n0 + r1) * HDIM + cc8;
  void* ad0 = smem + (w * 64) * 16;
  void* ad1 = smem + (256 + w * 64) * 16;
  void* bd0 = smem + 8192 + (w * 64) * 16;
  void* bd1 = smem + 8192 + (256 + w * 64) * 16;

  f32x4 acc[4][4] = {};
  const int wr = (w >> 1) * 64, wc = (w & 1) * 64;
  const int lr = lane & 15;
  const int kq = (lane >> 4) * 8;

  for (int k0 = 0; k0 < HDIM; k0 += 32) {
    __syncthreads();
    gload_lds16(a0 + k0, ad0);
    gload_lds16(a1 + k0, ad1);
    gload_lds16(bsrc0 + k0, bd0);
    gload_lds16(bsrc1 + k0, bd1);
    __syncthreads();
    bf16x8 af[4], bfr[4];
#pragma unroll
    for (int i = 0; i < 4; i++) af[i] = *(const bf16x8*)&As[(wr + i * 16 + lr) * 32 + kq];
#pragma unroll
    for (int j = 0; j < 4; j++) bfr[j] = *(const bf16x8*)&Bs[(wc + j * 16 + lr) * 32 + kq];
#pragma unroll
    for (int i = 0; i < 4; i++)
#pragma unroll
      for (int j = 0; j < 4; j++)
        acc[i][j] = __builtin_amdgcn_mfma_f32_16x16x32_bf16(af[i], bfr[j], acc[i][j], 0, 0, 0);
  }

  // ---- epilogue: scale by coef + LDS repack -> coalesced dwordx4 stores ----
  const int pbase = pb + m0;
  const float* b2e = b2 + (size_t)e * DDIM;
  float bvj[4];
#pragma unroll
  for (int j = 0; j < 4; j++) bvj[j] = b2e[n0 + wc + j * 16 + lr];

  const int rt = tid >> 2;
  const int chb = (tid & 3) * 8;
#pragma unroll
  for (int P = 0; P < 2; P++) {
    __syncthreads();
    if ((w >> 1) == P) {
#pragma unroll
      for (int i = 0; i < 4; i++) {
#pragma unroll
        for (int j = 0; j < 4; j++)
#pragma unroll
          for (int r = 0; r < 4; r++) {
            const int rrel = i * 16 + (lane >> 4) * 4 + r;
            const int m = P * 64 + rrel;
            const int col = wc + j * 16 + lr;
            stg[rrel * 136 + col] = __float2bfloat16(s_coef[m] * (acc[i][j][r] + bvj[j]));
          }
      }
    }
    __syncthreads();
    const int m = P * 64 + rt;
    if (m0 + m < cnt) {
      __hip_bfloat16* dst = ybuf + (size_t)(pbase + m) * DDIM + n0;
      const __hip_bfloat16* src = &stg[rt * 136];
#pragma unroll
      for (int c = 0; c < 4; c++)
        *(uint4*)(dst + chb + c * 32) = *(const uint4*)(src + chb + c * 32);
    }
  }
}

// ---------------- combine: out[t] = sum of token's selected ybuf rows ----------------
__global__ __launch_bounds__(256) void combine_kernel(
    const __hip_bfloat16* __restrict__ ybuf,    // [K_SEL][D]
    const unsigned* __restrict__ tcnt,
    const unsigned* __restrict__ tslot,
    const unsigned* __restrict__ exoff,
    float* __restrict__ out)                    // [S][D]
{
  const int tid = threadIdx.x;
  const int t = blockIdx.x * 2 + (tid >> 7);
  const int d0 = (tid & 127) * 8;
  float a[8] = {0, 0, 0, 0, 0, 0, 0, 0};
  const unsigned n = tcnt[t];
  for (unsigned s = 0; s < n; s++) {
    const unsigned code = tslot[t * 8u + s];
    const unsigned p = exoff[code >> 14] + (code & 16383u);
    bf16x8 v = *(const bf16x8*)(ybuf + (size_t)p * DDIM + d0);
#pragma unroll
    for (int k = 0; k < 8; k++)
      a[k] += __uint_as_float(((unsigned)(unsigned short)v[k]) << 16);
  }
  float* op = out + (size_t)t * DDIM + d0;
  *(float4*)op = make_float4(a[0], a[1], a[2], a[3]);
  *(float4*)(op + 4) = make_float4(a[4], a[5], a[6], a[7]);
}

// ---------------- launch ----------------
extern "C" void kernel_launch(void* const* d_in, const int* in_sizes, int n_in,
                              void* d_out, int out_size, void* d_ws, size_t ws_size,
                              hipStream_t stream) {
  const float* x    = (const float*)d_in[0];
  const float* gw   = (const float*)d_in[1];
  const float* bias = (const float*)d_in[2];
  const float* W1   = (const float*)d_in[3];
  const float* b1   = (const float*)d_in[4];
  const float* W2   = (const float*)d_in[5];
  const float* b2   = (const float*)d_in[6];
  float* out = (float*)d_out;
  char* ws = (char*)d_ws;

  if (ws_size < (size_t)WS_TOTAL) {
    fprintf(stderr, "kernel_launch: ws_size %zu < required %u\n", ws_size, WS_TOTAL);
    return;
  }

  unsigned* meta   = (unsigned*)(ws + WS_META);
  unsigned* hist   = (unsigned*)(ws + WS_HIST);
  unsigned* counts = (unsigned*)(ws + WS_COUNTS);
  unsigned* exoff  = (unsigned*)(ws + WS_EXOFF);
  unsigned* tiei   = (unsigned*)(ws + WS_TIEIDX);
  unsigned* tcnt   = (unsigned*)(ws + WS_TCNT);
  unsigned* tslot  = (unsigned*)(ws + WS_TSLOT);
  int*      tokl   = (int*)(ws + WS_TOK);
  float*    coefl  = (float*)(ws + WS_COEF);
  float*    scores = (float*)(ws + WS_SCORES);
  __hip_bfloat16* xb   = (__hip_bfloat16*)(ws + WS_XB);
  __hip_bfloat16* w1t  = (__hip_bfloat16*)(ws + WS_W1T);
  __hip_bfloat16* w2t  = (__hip_bfloat16*)(ws + WS_W2T);
  __hip_bfloat16* hbuf = (__hip_bfloat16*)(ws + WS_HBUF);
  __hip_bfloat16* ybuf = (__hip_bfloat16*)(ws + WS_YBUF);

  hipMemsetAsync(ws, 0, WS_CLEAR, stream);
  hipMemsetAsync(ws + WS_TCNT, 0, S_TOK * sizeof(unsigned), stream);

  // weight convert+transpose: W1 [E][D][H] -> [E][H][D]; W2 [E][H][D] -> [E][D][H]
  transpose_bf16_kernel<<<dim3(HDIM / 32, DDIM / 32, E_EXP), dim3(32, 8), 0, stream>>>(W1, w1t, DDIM, HDIM);
  transpose_bf16_kernel<<<dim3(DDIM / 32, HDIM / 32, E_EXP), dim3(32, 8), 0, stream>>>(W2, w2t, HDIM, DDIM);

  router_kernel<<<S_TOK / 4, 256, 0, stream>>>(x, gw, bias, scores, xb);

  // exact global top-k via 4-pass radix-8 select
  for (int p = 0; p < 4; p++) {
    hist_pass_kernel<<<ES / 2048, 256, 0, stream>>>(scores, meta, hist + p * 256, p);
    scan_pass_kernel<<<1, 256, 0, stream>>>(hist + p * 256, meta, p == 3);
  }
  sel_kernel<<<ES / 256, 256, 0, stream>>>(scores, meta, counts, tokl, coefl, tiei, tcnt, tslot);
  fin_kernel<<<1, 256, 0, stream>>>(meta, tiei, counts, tokl, coefl, tcnt, tslot);
  tail_kernel<<<1, 64, 0, stream>>>(counts, exoff, out + OUT_XO);

  gemm1_kernel<<<dim3(HDIM / 128, S_TOK / 128, E_EXP), 256, 0, stream>>>(
      xb, w1t, b1, tokl, counts, exoff, hbuf);
  // gemm2 writes ybuf over the (now dead) W1T region
  gemm2_kernel<<<dim3(DDIM / 128, S_TOK / 128, E_EXP), 256, 0, stream>>>(
      hbuf, w2t, b2, coefl, counts, exoff, ybuf);
  combine_kernel<<<S_TOK / 2, 256, 0, stream>>>(ybuf, tcnt, tslot, exoff, out);
}

// Round 4
// 954.708 us; speedup vs baseline: 2.1607x; 1.1339x over previous
//
#include <hip/hip_runtime.h>
#include <hip/hip_bf16.h>
#include <cstdint>
#include <cstdio>
#include <math.h>

// ---------------- problem constants ----------------
#define S_TOK 16384     // B*SEQ
#define E_EXP 8
#define DDIM  1024
#define HDIM  4096
#define K_SEL 32768     // int(S * 2.0)
#define ES    131072    // E * S
#define OUT_XO 16777216 // S*D

// ---------------- workspace layout (bytes) ----------------
#define WS_META    0x000000u   // 16 u32
#define WS_HIST    0x000100u   // 4 passes x 256 u32
#define WS_COUNTS  0x001100u   // 8 u32
#define WS_EXOFF   0x001200u   // 9 u32
#define WS_TIEIDX  0x001300u   // 8192 u32
#define WS_CLEAR   0x00A000u
#define WS_TOK     0x010000u   // E*S int
#define WS_COEF    0x090000u   // E*S float
#define WS_SCORES  0x110000u   // E*S float
#define WS_TCNT    0x190000u   // S u32
#define WS_TSLOT   0x1A0000u   // S*8 u32
#define WS_XB      0x400000u   // S*D bf16 (32MB)
#define WS_W1T    0x2400000u   // E*H*D bf16 (64MB)  [aliased as ybuf after gemm1]
#define WS_W2T    0x6400000u   // E*D*H bf16 (64MB)
#define WS_HBUF   0xA400000u   // K_SEL*H bf16 (256MB)
#define WS_TOTAL  0x1A400000u
#define WS_YBUF   WS_W1T

typedef __attribute__((ext_vector_type(4))) float f32x4;
typedef __attribute__((ext_vector_type(8))) short bf16x8;

__device__ __forceinline__ void gload_lds16(const void* g, void* l) {
  __builtin_amdgcn_global_load_lds((const __attribute__((address_space(1))) void*)g,
                                   (__attribute__((address_space(3))) void*)l, 16, 0, 0);
}

__device__ __forceinline__ float gelu_f(float x) {
  float u = __builtin_fmaf(x * x * x, 0.044715f, x);
  float e = __builtin_amdgcn_exp2f(-2.302207976f * u);
  return x * __builtin_amdgcn_rcpf(1.0f + e);
}

// ================= 8-phase 256^2 GEMM machinery =================
// LDS: A dbuf0 @0, A dbuf1 @32768, B dbuf0 @65536, B dbuf1 @98304; halves +16384.
// Swizzle: LDS row r (128B), 16B-chunk c holds logical chunk c ^ (r&7).
// Stage side: linear LDS dest, global source chunk pre-swizzled per lane.
#define ABUF0 0
#define ABUF1 32768
#define BBUF0 65536
#define BBUF1 98304
#define HALF  16384

#define PH_BAR() __builtin_amdgcn_s_barrier()
#define SB0()    __builtin_amdgcn_sched_barrier(0)
#define LGK0()   do { asm volatile("s_waitcnt lgkmcnt(0)"); __builtin_amdgcn_sched_barrier(0); } while (0)
#define VMC6()   asm volatile("s_waitcnt vmcnt(6)")
#define VMC0()   asm volatile("s_waitcnt vmcnt(0)")

// stage one A/B half-tile (this thread's 2 gload_lds); KE = k offset in elems
#define GLA(DSTOFF, KE, H) do { \
  gload_lds16(aS##H##0 + (KE), lds + (DSTOFF) + w * 2048); \
  gload_lds16(aS##H##1 + (KE), lds + (DSTOFF) + w * 2048 + 1024); } while (0)
#define GLB(DSTOFF, KE, H) do { \
  gload_lds16(bS##H##0 + (KE), lds + (DSTOFF) + w * 2048); \
  gload_lds16(bS##H##1 + (KE), lds + (DSTOFF) + w * 2048 + 1024); } while (0)

#define LOAD_A(AB, ILO) do { _Pragma("unroll") for (int ii = 0; ii < 4; ii++) { \
  aF[ii][0] = *(const bf16x8*)(lds + (AB) + arow + ((ILO) + ii) * 2048 + pc0); \
  aF[ii][1] = *(const bf16x8*)(lds + (AB) + arow + ((ILO) + ii) * 2048 + pc1); } } while (0)
#define LOAD_B(BB) do { _Pragma("unroll") for (int jj = 0; jj < 4; jj++) { \
  bF[jj][0] = *(const bf16x8*)(lds + (BB) + brow + jj * 2048 + pc0); \
  bF[jj][1] = *(const bf16x8*)(lds + (BB) + brow + jj * 2048 + pc1); } } while (0)

#define MFMA_Q(ILO, JLO) do { _Pragma("unroll") for (int ii = 0; ii < 4; ii++) \
  _Pragma("unroll") for (int jj = 0; jj < 2; jj++) { \
    acc[(ILO)+ii][(JLO)+jj] = __builtin_amdgcn_mfma_f32_16x16x32_bf16(aF[ii][0], bF[(JLO)+jj][0], acc[(ILO)+ii][(JLO)+jj], 0, 0, 0); \
    acc[(ILO)+ii][(JLO)+jj] = __builtin_amdgcn_mfma_f32_16x16x32_bf16(aF[ii][1], bF[(JLO)+jj][1], acc[(ILO)+ii][(JLO)+jj], 0, 0, 0); } } while (0)

// One K-tile = 4 phases. Stage plan (derived-safe vs overwrite races):
//  P0: read A[0..3]+B[all] ; stage (t+1).Ah1 -> other A buf
//  P1:                     ; stage (t+2).Bh0 -> this B buf
//  P2: read A[4..7]        ; stage (t+2).Bh1
//  P3:                     ; stage (t+2).Ah0 ; ENDWAIT ; barrier
#define KGROUP(K0, AB, BB, AO, P0STG, STG, ENDWAIT) do { \
  LOAD_A(AB, 0); LOAD_B(BB); \
  if (P0STG) { GLA((AO) + HALF, (K0) + 64, 1); } \
  PH_BAR(); LGK0(); \
  __builtin_amdgcn_s_setprio(1); MFMA_Q(0, 0); __builtin_amdgcn_s_setprio(0); \
  PH_BAR(); SB0(); \
  if (STG) { GLB((BB), (K0) + 128, 0); } \
  PH_BAR(); LGK0(); \
  __builtin_amdgcn_s_setprio(1); MFMA_Q(0, 2); __builtin_amdgcn_s_setprio(0); \
  PH_BAR(); SB0(); \
  LOAD_A(AB, 4); \
  if (STG) { GLB((BB) + HALF, (K0) + 128, 1); } \
  PH_BAR(); LGK0(); \
  __builtin_amdgcn_s_setprio(1); MFMA_Q(4, 2); __builtin_amdgcn_s_setprio(0); \
  PH_BAR(); SB0(); \
  if (STG) { GLA((AB), (K0) + 128, 0); } \
  PH_BAR(); LGK0(); \
  __builtin_amdgcn_s_setprio(1); MFMA_Q(4, 0); __builtin_amdgcn_s_setprio(0); \
  ENDWAIT; \
  PH_BAR(); SB0(); \
} while (0)

// ---------------- weight transpose + fp32->bf16 ----------------
__global__ __launch_bounds__(256) void transpose_bf16_kernel(
    const float* __restrict__ in, __hip_bfloat16* __restrict__ outp, int R, int C)
{
  __shared__ float tile[32][33];
  const int c0 = blockIdx.x * 32, r0 = blockIdx.y * 32;
  const size_t eoff = (size_t)blockIdx.z * (size_t)R * (size_t)C;
  const float* ip = in + eoff;
  __hip_bfloat16* op = outp + eoff;
  const int tx = threadIdx.x, ty = threadIdx.y;
#pragma unroll
  for (int i = 0; i < 4; i++) {
    int r = ty + i * 8;
    tile[r][tx] = ip[(size_t)(r0 + r) * C + c0 + tx];
  }
  __syncthreads();
#pragma unroll
  for (int i = 0; i < 4; i++) {
    int c = ty + i * 8;
    op[(size_t)(c0 + c) * R + r0 + tx] = __float2bfloat16(tile[tx][c]);
  }
}

// ---------------- router ----------------
__global__ __launch_bounds__(256) void router_kernel(
    const float* __restrict__ x, const float* __restrict__ gw, const float* __restrict__ bias,
    float* __restrict__ scores, __hip_bfloat16* __restrict__ xb)
{
  __shared__ float g[E_EXP * DDIM];
  __shared__ float bs[E_EXP];
  const int tid = threadIdx.x;
  for (int i = tid; i < E_EXP * DDIM; i += 256) g[i] = gw[i];
  if (tid < E_EXP) bs[tid] = bias[tid];
  __syncthreads();
  const int w = tid >> 6, lane = tid & 63;
  const int s = blockIdx.x * 4 + w;
  double acc[E_EXP] = {0, 0, 0, 0, 0, 0, 0, 0};
  const float* xrow = x + (size_t)s * DDIM;
  __hip_bfloat16* xbrow = xb + (size_t)s * DDIM;
#pragma unroll 4
  for (int j = 0; j < 16; j++) {
    int d = lane + 64 * j;
    float xv = xrow[d];
    xbrow[d] = __float2bfloat16(xv);
#pragma unroll
    for (int e = 0; e < E_EXP; e++) acc[e] += (double)xv * (double)g[e * DDIM + d];
  }
#pragma unroll
  for (int e = 0; e < E_EXP; e++) {
    double a = acc[e];
#pragma unroll
    for (int off = 32; off > 0; off >>= 1) a += __shfl_xor(a, off);
    acc[e] = a;
  }
  if (lane == 0) {
#pragma unroll
    for (int e = 0; e < E_EXP; e++) {
      double lg = acc[e] + (double)bs[e];
      float sc = (float)(1.0 / (1.0 + exp(-lg)));
      scores[(size_t)e * S_TOK + s] = sc;
    }
  }
}

// ---------------- radix-8 select ----------------
__global__ __launch_bounds__(256) void hist_pass_kernel(
    const float* __restrict__ scores, const unsigned* __restrict__ meta,
    unsigned* __restrict__ hist, int pass)
{
  __shared__ unsigned h[256];
  const int tid = threadIdx.x;
  h[tid] = 0;
  __syncthreads();
  const unsigned prefix = meta[0];
  const int pshift = 32 - 8 * pass;
  const int bshift = 24 - 8 * pass;
  const unsigned base = blockIdx.x * 2048 + tid;
#pragma unroll
  for (int i = 0; i < 8; i++) {
    unsigned b = __float_as_uint(scores[base + i * 256]);
    bool ok = (pass == 0) || ((b >> pshift) == prefix);
    if (ok) atomicAdd(&h[(b >> bshift) & 0xFFu], 1u);
  }
  __syncthreads();
  if (h[tid]) atomicAdd(&hist[tid], h[tid]);
}

__global__ __launch_bounds__(256) void scan_pass_kernel(
    const unsigned* __restrict__ hist, unsigned* __restrict__ meta, int final)
{
  const int t = threadIdx.x;
  const unsigned v = hist[t];
  const unsigned prefix = meta[0];
  const unsigned above = meta[1];
  __shared__ unsigned csum[256];
  csum[t] = v;
  __syncthreads();
  for (int off = 1; off < 256; off <<= 1) {
    unsigned add = (t + off < 256) ? csum[t + off] : 0u;
    __syncthreads();
    csum[t] += add;
    __syncthreads();
  }
  const unsigned cge = csum[t];
  const unsigned cgt = cge - v;
  if (above + cgt < K_SEL && above + cge >= K_SEL) {
    meta[0] = (prefix << 8) | (unsigned)t;
    meta[1] = above + cgt;
    if (final) {
      meta[2] = (prefix << 8) | (unsigned)t;
      meta[4] = K_SEL - (above + cgt);
    }
  }
}

__global__ __launch_bounds__(256) void sel_kernel(const float* __restrict__ scores,
                                                  unsigned* __restrict__ meta,
                                                  unsigned* __restrict__ counts,
                                                  int* __restrict__ tok_list,
                                                  float* __restrict__ coef_list,
                                                  unsigned* __restrict__ tie_idx,
                                                  unsigned* __restrict__ tcnt,
                                                  unsigned* __restrict__ tslot)
{
  __shared__ unsigned lcnt[E_EXP], lbase[E_EXP];
  const int tid = threadIdx.x;
  if (tid < E_EXP) lcnt[tid] = 0;
  __syncthreads();
  const unsigned i = blockIdx.x * 256 + tid;
  const float v = scores[i];
  const unsigned b = __float_as_uint(v);
  const unsigned t = meta[2];
  const bool sel = (b > t);
  const unsigned e = i >> 14;
  unsigned myslot = 0;
  if (sel) myslot = atomicAdd(&lcnt[e], 1u);
  else if (b == t) {
    unsigned ts = atomicAdd(&meta[5], 1u);
    if (ts < 8192u) tie_idx[ts] = i;
  }
  __syncthreads();
  if (tid < E_EXP) lbase[tid] = atomicAdd(&counts[tid], lcnt[tid]);
  __syncthreads();
  if (sel) {
    const unsigned slot = lbase[e] + myslot;
    const unsigned p = e * S_TOK + slot;
    const unsigned tok = i & 16383u;
    tok_list[p] = (int)tok;
    coef_list[p] = v;
    unsigned us = atomicAdd(&tcnt[tok], 1u);
    tslot[tok * 8u + us] = (e << 14) | slot;
  }
}

__global__ __launch_bounds__(256) void fin_kernel(const unsigned* __restrict__ meta,
                                                  const unsigned* __restrict__ tie_idx,
                                                  unsigned* __restrict__ counts,
                                                  int* __restrict__ tok_list,
                                                  float* __restrict__ coef_list,
                                                  unsigned* __restrict__ tcnt,
                                                  unsigned* __restrict__ tslot)
{
  unsigned tcnt_ties = meta[5]; if (tcnt_ties > 8192u) tcnt_ties = 8192u;
  const unsigned q = meta[4];
  const float tval = __uint_as_float(meta[2]);
  for (unsigned t = threadIdx.x; t < tcnt_ties; t += 256) {
    unsigned idx = tie_idx[t];
    unsigned rank = 0;
    for (unsigned u = 0; u < tcnt_ties; u++) rank += (tie_idx[u] < idx) ? 1u : 0u;
    if (rank < q) {
      const unsigned e = idx >> 14;
      const unsigned tok = idx & 16383u;
      const unsigned slot = atomicAdd(&counts[e], 1u);
      tok_list[e * S_TOK + slot] = (int)tok;
      coef_list[e * S_TOK + slot] = tval;
      unsigned us = atomicAdd(&tcnt[tok], 1u);
      tslot[tok * 8u + us] = (e << 14) | slot;
    }
  }
}

__global__ void tail_kernel(const unsigned* __restrict__ counts, unsigned* __restrict__ exoff,
                            float* __restrict__ tail)
{
  if (threadIdx.x == 0) {
    unsigned o = 0;
    for (int e = 0; e < E_EXP; e++) { exoff[e] = o; o += counts[e]; }
    exoff[E_EXP] = o;
  }
  if (threadIdx.x < E_EXP) {
    tail[threadIdx.x] = (float)counts[threadIdx.x] * (1.0f / (float)K_SEL);
    tail[E_EXP + threadIdx.x] = 1.0f;
  }
}

// ---------------- GEMM1: hbuf = gelu(Xg @ W1 + b1), 256^2 8-phase ----------------
__global__ __launch_bounds__(512, 1) void gemm1_kernel(
    const __hip_bfloat16* __restrict__ xb,      // [S][D]
    const __hip_bfloat16* __restrict__ w1t,     // [E][H][D]
    const float* __restrict__ b1,               // [E][H]
    const int* __restrict__ tok_list,           // [E][S]
    const unsigned* __restrict__ counts,
    const unsigned* __restrict__ exoff,
    __hip_bfloat16* __restrict__ hbuf)          // [K_SEL][H]
{
  const int e = blockIdx.z;
  const int cnt = (int)counts[e];
  const int m0 = blockIdx.y * 256;
  if (m0 >= cnt) return;
  const int n0 = blockIdx.x * 256;

  __shared__ __align__(16) char lds[131072];
  __shared__ int s_tok[256];

  const int tid = threadIdx.x;
  const int w = tid >> 6, lane = tid & 63;
  const int wm = w >> 2, wn = w & 3;

  if (tid < 256) {
    int mi = m0 + tid;
    s_tok[tid] = tok_list[e * S_TOK + (mi < cnt ? mi : cnt - 1)];
  }
  __syncthreads();

  // stage-side per-thread pointers (pre-swizzled global chunk)
  const int srl0 = w * 16 + (lane >> 3);
  const int srl1 = srl0 + 8;
  const int gch = ((lane & 7) ^ (lane >> 3)) * 8;   // elems
  const __hip_bfloat16* aS00 = xb + (size_t)s_tok[srl0] * DDIM + gch;
  const __hip_bfloat16* aS01 = xb + (size_t)s_tok[srl1] * DDIM + gch;
  const __hip_bfloat16* aS10 = xb + (size_t)s_tok[128 + srl0] * DDIM + gch;
  const __hip_bfloat16* aS11 = xb + (size_t)s_tok[128 + srl1] * DDIM + gch;
  const __hip_bfloat16* w1e = w1t + (size_t)e * HDIM * DDIM;
  const __hip_bfloat16* bS00 = w1e + (size_t)(n0 + srl0) * DDIM + gch;
  const __hip_bfloat16* bS01 = w1e + (size_t)(n0 + srl1) * DDIM + gch;
  const __hip_bfloat16* bS10 = w1e + (size_t)(n0 + 128 + srl0) * DDIM + gch;
  const __hip_bfloat16* bS11 = w1e + (size_t)(n0 + 128 + srl1) * DDIM + gch;

  // read-side constants
  const int arow = (wm * 128 + (lane & 15)) * 128;  // bytes
  const int brow = (wn * 64 + (lane & 15)) * 128;
  const int pc0 = (((lane >> 4)) ^ (lane & 7)) * 16;
  const int pc1 = (((lane >> 4) + 4) ^ (lane & 7)) * 16;

  f32x4 acc[8][4] = {};
  bf16x8 aF[4][2], bF[4][2];

  // prologue: t0 full (4 halves) + t1 {Bh0,Bh1,Ah0}
  GLA(ABUF0, 0, 0); GLA(ABUF0 + HALF, 0, 1);
  GLB(BBUF0, 0, 0); GLB(BBUF0 + HALF, 0, 1);
  GLB(BBUF1, 64, 0); GLB(BBUF1 + HALF, 64, 1);
  GLA(ABUF1, 64, 0);
  VMC6(); PH_BAR(); SB0();

  const int NKT = DDIM / 64;  // 16
  int kt = 0;
  for (; kt + 2 < NKT; kt += 2) {
    KGROUP(kt * 64, ABUF0, BBUF0, ABUF1, true, true, VMC6());
    KGROUP((kt + 1) * 64, ABUF1, BBUF1, ABUF0, true, true, VMC6());
  }
  KGROUP(kt * 64, ABUF0, BBUF0, ABUF1, true, false, VMC0());
  KGROUP((kt + 1) * 64, ABUF1, BBUF1, ABUF0, false, false, );
  VMC0();
  __syncthreads();

  // ---- epilogue: gelu + LDS repack -> coalesced stores ----
  __hip_bfloat16* stg = (__hip_bfloat16*)lds;
  const float* b1e = b1 + (size_t)e * HDIM;
  float bvj[4];
#pragma unroll
  for (int j = 0; j < 4; j++) bvj[j] = b1e[n0 + wn * 64 + j * 16 + (lane & 15)];
  const int pbase = (int)exoff[e] + m0;

#pragma unroll
  for (int P = 0; P < 4; P++) {
    __syncthreads();
    if (wm == (P >> 1)) {
      const int ib = (P & 1) * 4;
#pragma unroll
      for (int ii = 0; ii < 4; ii++)
#pragma unroll
        for (int jj = 0; jj < 4; jj++)
#pragma unroll
          for (int r = 0; r < 4; r++) {
            const int rloc = ii * 16 + (lane >> 4) * 4 + r;
            const int col = wn * 64 + jj * 16 + (lane & 15);
            stg[rloc * 264 + col] = __float2bfloat16(gelu_f(acc[ib + ii][jj][r] + bvj[jj]));
          }
    }
    __syncthreads();
    const int rr = tid >> 3;
    const int m = P * 64 + rr;
    if (m0 + m < cnt) {
      __hip_bfloat16* dst = hbuf + (size_t)(pbase + m) * HDIM + n0;
      const __hip_bfloat16* src = stg + rr * 264;
#pragma unroll
      for (int c = 0; c < 4; c++)
        *(uint4*)(dst + (tid & 7) * 8 + c * 64) = *(const uint4*)(src + (tid & 7) * 8 + c * 64);
    }
  }
}

// ---------------- GEMM2: ybuf[slot] = coef * (H @ W2 + b2), 256^2 8-phase ----------------
__global__ __launch_bounds__(512, 1) void gemm2_kernel(
    const __hip_bfloat16* __restrict__ hbuf,    // [K_SEL][H]
    const __hip_bfloat16* __restrict__ w2t,     // [E][D][H]
    const float* __restrict__ b2,               // [E][D]
    const float* __restrict__ coef_list,
    const unsigned* __restrict__ counts,
    const unsigned* __restrict__ exoff,
    __hip_bfloat16* __restrict__ ybuf)          // [K_SEL][D]
{
  const int e = blockIdx.z;
  const int cnt = (int)counts[e];
  const int m0 = blockIdx.y * 256;
  if (m0 >= cnt) return;
  const int n0 = blockIdx.x * 256;

  __shared__ __align__(16) char lds[131072];
  __shared__ float s_coef[256];

  const int tid = threadIdx.x;
  const int w = tid >> 6, lane = tid & 63;
  const int wm = w >> 2, wn = w & 3;
  const int pb = (int)exoff[e];

  if (tid < 256) {
    int mi = m0 + tid;
    s_coef[tid] = (mi < cnt) ? coef_list[e * S_TOK + mi] : 0.0f;
  }
  __syncthreads();

  const int srl0 = w * 16 + (lane >> 3);
  const int srl1 = srl0 + 8;
  const int gch = ((lane & 7) ^ (lane >> 3)) * 8;
  const int ra0 = pb + ((m0 + srl0 < cnt) ? m0 + srl0 : cnt - 1);
  const int ra1 = pb + ((m0 + srl1 < cnt) ? m0 + srl1 : cnt - 1);
  const int ra2 = pb + ((m0 + 128 + srl0 < cnt) ? m0 + 128 + srl0 : cnt - 1);
  const int ra3 = pb + ((m0 + 128 + srl1 < cnt) ? m0 + 128 + srl1 : cnt - 1);
  const __hip_bfloat16* aS00 = hbuf + (size_t)ra0 * HDIM + gch;
  const __hip_bfloat16* aS01 = hbuf + (size_t)ra1 * HDIM + gch;
  const __hip_bfloat16* aS10 = hbuf + (size_t)ra2 * HDIM + gch;
  const __hip_bfloat16* aS11 = hbuf + (size_t)ra3 * HDIM + gch;
  const __hip_bfloat16* w2e = w2t + (size_t)e * DDIM * HDIM;
  const __hip_bfloat16* bS00 = w2e + (size_t)(n0 + srl0) * HDIM + gch;
  const __hip_bfloat16* bS01 = w2e + (size_t)(n0 + srl1) * HDIM + gch;
  const __hip_bfloat16* bS10 = w2e + (size_t)(n0 + 128 + srl0) * HDIM + gch;
  const __hip_bfloat16* bS11 = w2e + (size_t)(n0 + 128 + srl1) * HDIM + gch;

  const int arow = (wm * 128 + (lane & 15)) * 128;
  const int brow = (wn * 64 + (lane & 15)) * 128;
  const int pc0 = (((lane >> 4)) ^ (lane & 7)) * 16;
  const int pc1 = (((lane >> 4) + 4) ^ (lane & 7)) * 16;

  f32x4 acc[8][4] = {};
  bf16x8 aF[4][2], bF[4][2];

  GLA(ABUF0, 0, 0); GLA(ABUF0 + HALF, 0, 1);
  GLB(BBUF0, 0, 0); GLB(BBUF0 + HALF, 0, 1);
  GLB(BBUF1, 64, 0); GLB(BBUF1 + HALF, 64, 1);
  GLA(ABUF1, 64, 0);
  VMC6(); PH_BAR(); SB0();

  const int NKT = HDIM / 64;  // 64
  int kt = 0;
  for (; kt + 2 < NKT; kt += 2) {
    KGROUP(kt * 64, ABUF0, BBUF0, ABUF1, true, true, VMC6());
    KGROUP((kt + 1) * 64, ABUF1, BBUF1, ABUF0, true, true, VMC6());
  }
  KGROUP(kt * 64, ABUF0, BBUF0, ABUF1, true, false, VMC0());
  KGROUP((kt + 1) * 64, ABUF1, BBUF1, ABUF0, false, false, );
  VMC0();
  __syncthreads();

  // ---- epilogue: coef scale + LDS repack -> coalesced stores ----
  __hip_bfloat16* stg = (__hip_bfloat16*)lds;
  const float* b2e = b2 + (size_t)e * DDIM;
  float bvj[4];
#pragma unroll
  for (int j = 0; j < 4; j++) bvj[j] = b2e[n0 + wn * 64 + j * 16 + (lane & 15)];
  const int pbase = pb + m0;

#pragma unroll
  for (int P = 0; P < 4; P++) {
    __syncthreads();
    if (wm == (P >> 1)) {
      const int ib = (P & 1) * 4;
#pragma unroll
      for (int ii = 0; ii < 4; ii++)
#pragma unroll
        for (int jj = 0; jj < 4; jj++)
#pragma unroll
          for (int r = 0; r < 4; r++) {
            const int rloc = ii * 16 + (lane >> 4) * 4 + r;
            const int col = wn * 64 + jj * 16 + (lane & 15);
            const float cf = s_coef[P * 64 + rloc];
            stg[rloc * 264 + col] = __float2bfloat16(cf * (acc[ib + ii][jj][r] + bvj[jj]));
          }
    }
    __syncthreads();
    const int rr = tid >> 3;
    const int m = P * 64 + rr;
    if (m0 + m < cnt) {
      __hip_bfloat16* dst = ybuf + (size_t)(pbase + m) * DDIM + n0;
      const __hip_bfloat16* src = stg + rr * 264;
#pragma unroll
      for (int c = 0; c < 4; c++)
        *(uint4*)(dst + (tid & 7) * 8 + c * 64) = *(const uint4*)(src + (tid & 7) * 8 + c * 64);
    }
  }
}

// ---------------- combine ----------------
__global__ __launch_bounds__(256) void combine_kernel(
    const __hip_bfloat16* __restrict__ ybuf,    // [K_SEL][D]
    const unsigned* __restrict__ tcnt,
    const unsigned* __restrict__ tslot,
    const unsigned* __restrict__ exoff,
    float* __restrict__ out)                    // [S][D]
{
  const int tid = threadIdx.x;
  const int t = blockIdx.x * 2 + (tid >> 7);
  const int d0 = (tid & 127) * 8;
  float a[8] = {0, 0, 0, 0, 0, 0, 0, 0};
  const unsigned n = tcnt[t];
  for (unsigned s = 0; s < n; s++) {
    const unsigned code = tslot[t * 8u + s];
    const unsigned p = exoff[code >> 14] + (code & 16383u);
    bf16x8 v = *(const bf16x8*)(ybuf + (size_t)p * DDIM + d0);
#pragma unroll
    for (int k = 0; k < 8; k++)
      a[k] += __uint_as_float(((unsigned)(unsigned short)v[k]) << 16);
  }
  float* op = out + (size_t)t * DDIM + d0;
  *(float4*)op = make_float4(a[0], a[1], a[2], a[3]);
  *(float4*)(op + 4) = make_float4(a[4], a[5], a[6], a[7]);
}

// ---------------- launch ----------------
extern "C" void kernel_launch(void* const* d_in, const int* in_sizes, int n_in,
                              void* d_out, int out_size, void* d_ws, size_t ws_size,
                              hipStream_t stream) {
  const float* x    = (const float*)d_in[0];
  const float* gw   = (const float*)d_in[1];
  const float* bias = (const float*)d_in[2];
  const float* W1   = (const float*)d_in[3];
  const float* b1   = (const float*)d_in[4];
  const float* W2   = (const float*)d_in[5];
  const float* b2   = (const float*)d_in[6];
  float* out = (float*)d_out;
  char* ws = (char*)d_ws;

  if (ws_size < (size_t)WS_TOTAL) {
    fprintf(stderr, "kernel_launch: ws_size %zu < required %u\n", ws_size, WS_TOTAL);
    return;
  }

  unsigned* meta   = (unsigned*)(ws + WS_META);
  unsigned* hist   = (unsigned*)(ws + WS_HIST);
  unsigned* counts = (unsigned*)(ws + WS_COUNTS);
  unsigned* exoff  = (unsigned*)(ws + WS_EXOFF);
  unsigned* tiei   = (unsigned*)(ws + WS_TIEIDX);
  unsigned* tcnt   = (unsigned*)(ws + WS_TCNT);
  unsigned* tslot  = (unsigned*)(ws + WS_TSLOT);
  int*      tokl   = (int*)(ws + WS_TOK);
  float*    coefl  = (float*)(ws + WS_COEF);
  float*    scores = (float*)(ws + WS_SCORES);
  __hip_bfloat16* xb   = (__hip_bfloat16*)(ws + WS_XB);
  __hip_bfloat16* w1t  = (__hip_bfloat16*)(ws + WS_W1T);
  __hip_bfloat16* w2t  = (__hip_bfloat16*)(ws + WS_W2T);
  __hip_bfloat16* hbuf = (__hip_bfloat16*)(ws + WS_HBUF);
  __hip_bfloat16* ybuf = (__hip_bfloat16*)(ws + WS_YBUF);

  hipMemsetAsync(ws, 0, WS_CLEAR, stream);
  hipMemsetAsync(ws + WS_TCNT, 0, S_TOK * sizeof(unsigned), stream);

  transpose_bf16_kernel<<<dim3(HDIM / 32, DDIM / 32, E_EXP), dim3(32, 8), 0, stream>>>(W1, w1t, DDIM, HDIM);
  transpose_bf16_kernel<<<dim3(DDIM / 32, HDIM / 32, E_EXP), dim3(32, 8), 0, stream>>>(W2, w2t, HDIM, DDIM);

  router_kernel<<<S_TOK / 4, 256, 0, stream>>>(x, gw, bias, scores, xb);

  for (int p = 0; p < 4; p++) {
    hist_pass_kernel<<<ES / 2048, 256, 0, stream>>>(scores, meta, hist + p * 256, p);
    scan_pass_kernel<<<1, 256, 0, stream>>>(hist + p * 256, meta, p == 3);
  }
  sel_kernel<<<ES / 256, 256, 0, stream>>>(scores, meta, counts, tokl, coefl, tiei, tcnt, tslot);
  fin_kernel<<<1, 256, 0, stream>>>(meta, tiei, counts, tokl, coefl, tcnt, tslot);
  tail_kernel<<<1, 64, 0, stream>>>(counts, exoff, out + OUT_XO);

  gemm1_kernel<<<dim3(HDIM / 256, S_TOK / 256, E_EXP), 512, 0, stream>>>(
      xb, w1t, b1, tokl, counts, exoff, hbuf);
  gemm2_kernel<<<dim3(DDIM / 256, S_TOK / 256, E_EXP), 512, 0, stream>>>(
      hbuf, w2t, b2, coefl, counts, exoff, ybuf);
  combine_kernel<<<S_TOK / 2, 256, 0, stream>>>(ybuf, tcnt, tslot, exoff, out);
}

// Round 5
// 947.034 us; speedup vs baseline: 2.1782x; 1.0081x over previous
//
#include <hip/hip_runtime.h>
#include <hip/hip_bf16.h>
#include <cstdint>
#include <cstdio>
#include <math.h>

// ---------------- problem constants ----------------
#define S_TOK 16384     // B*SEQ
#define E_EXP 8
#define DDIM  1024
#define HDIM  4096
#define K_SEL 32768     // int(S * 2.0)
#define ES    131072    // E * S
#define OUT_XO 16777216 // S*D

// ---------------- workspace layout (bytes) ----------------
#define WS_META    0x000000u   // 16 u32
#define WS_HIST    0x000100u   // 4 passes x 256 u32
#define WS_COUNTS  0x001100u   // 8 u32
#define WS_EXOFF   0x001200u   // 9 u32
#define WS_TIEIDX  0x001300u   // 8192 u32
#define WS_CLEAR   0x00A000u
#define WS_TOK     0x010000u   // E*S int
#define WS_COEF    0x090000u   // E*S float
#define WS_SCORES  0x110000u   // E*S float
#define WS_TCNT    0x190000u   // S u32
#define WS_TSLOT   0x1A0000u   // S*8 u32
#define WS_XB      0x400000u   // S*D bf16 (32MB)
#define WS_W1T    0x2400000u   // E*H*D bf16 (64MB)  [aliased as ybuf after gemm1]
#define WS_W2T    0x6400000u   // E*D*H bf16 (64MB)
#define WS_HBUF   0xA400000u   // K_SEL*H bf16 (256MB)
#define WS_TOTAL  0x1A400000u
#define WS_YBUF   WS_W1T

typedef __attribute__((ext_vector_type(4))) float f32x4;
typedef __attribute__((ext_vector_type(8))) short bf16x8;

__device__ __forceinline__ void gload_lds16(const void* g, void* l) {
  __builtin_amdgcn_global_load_lds((const __attribute__((address_space(1))) void*)g,
                                   (__attribute__((address_space(3))) void*)l, 16, 0, 0);
}

__device__ __forceinline__ float gelu_f(float x) {
  float u = __builtin_fmaf(x * x * x, 0.044715f, x);
  float e = __builtin_amdgcn_exp2f(-2.302207976f * u);
  return x * __builtin_amdgcn_rcpf(1.0f + e);
}

// ================= 2-phase/tile 256^2 GEMM machinery =================
// LDS: A buf0 @0, A buf1 @32768, B buf0 @65536, B buf1 @98304; halves +16384.
// Swizzle: 16B chunk c of a 128B row r holds logical chunk c ^ (r&7);
// stage side pre-swizzles the GLOBAL source chunk, LDS dest stays linear.
#define ABUF0 0
#define ABUF1 32768
#define BBUF0 65536
#define BBUF1 98304
#define HALF  16384

#define PH_BAR() __builtin_amdgcn_s_barrier()
#define VMC0M()  asm volatile("s_waitcnt vmcnt(0)" ::: "memory")

// stage one full 256-row tile half-pair (4 gloads: h0 rows, h1 rows)
#define STAGE_A(DST, KE) do { \
  gload_lds16(aS00 + (KE), lds + (DST) + w * 2048); \
  gload_lds16(aS01 + (KE), lds + (DST) + w * 2048 + 1024); \
  gload_lds16(aS10 + (KE), lds + (DST) + HALF + w * 2048); \
  gload_lds16(aS11 + (KE), lds + (DST) + HALF + w * 2048 + 1024); } while (0)
#define STAGE_B(DST, KE) do { \
  gload_lds16(bS00 + (KE), lds + (DST) + w * 2048); \
  gload_lds16(bS01 + (KE), lds + (DST) + w * 2048 + 1024); \
  gload_lds16(bS10 + (KE), lds + (DST) + HALF + w * 2048); \
  gload_lds16(bS11 + (KE), lds + (DST) + HALF + w * 2048 + 1024); } while (0)

#define LDS_A03(AB) { _Pragma("unroll") for (int ii = 0; ii < 4; ii++) { \
  a03[ii][0] = *(const bf16x8*)(lds + (AB) + arow + ii * 2048 + pc0); \
  a03[ii][1] = *(const bf16x8*)(lds + (AB) + arow + ii * 2048 + pc1); } }
#define LDS_A47(AB) { _Pragma("unroll") for (int ii = 0; ii < 4; ii++) { \
  a47[ii][0] = *(const bf16x8*)(lds + (AB) + arow + (4 + ii) * 2048 + pc0); \
  a47[ii][1] = *(const bf16x8*)(lds + (AB) + arow + (4 + ii) * 2048 + pc1); } }
#define LDS_B01(BB) { _Pragma("unroll") for (int jj = 0; jj < 2; jj++) { \
  b01[jj][0] = *(const bf16x8*)(lds + (BB) + brow + jj * 2048 + pc0); \
  b01[jj][1] = *(const bf16x8*)(lds + (BB) + brow + jj * 2048 + pc1); } }
#define LDS_B23(BB) { _Pragma("unroll") for (int jj = 0; jj < 2; jj++) { \
  b23[jj][0] = *(const bf16x8*)(lds + (BB) + brow + (2 + jj) * 2048 + pc0); \
  b23[jj][1] = *(const bf16x8*)(lds + (BB) + brow + (2 + jj) * 2048 + pc1); } }

#define MF(AA, BF, IL, JL) { _Pragma("unroll") for (int ii = 0; ii < 4; ii++) \
  _Pragma("unroll") for (int jj = 0; jj < 2; jj++) { \
    acc[(IL)+ii][(JL)+jj] = __builtin_amdgcn_mfma_f32_16x16x32_bf16(AA[ii][0], BF[jj][0], acc[(IL)+ii][(JL)+jj], 0, 0, 0); \
    acc[(IL)+ii][(JL)+jj] = __builtin_amdgcn_mfma_f32_16x16x32_bf16(AA[ii][1], BF[jj][1], acc[(IL)+ii][(JL)+jj], 0, 0, 0); } }

// One K-tile, 2 phases.  P0: dsr A03(t) | stage Ah(t+1) | MFMA a03xB | vmcnt0
//                        P1: dsr A47(t) | stage Bh(t+2) | MFMA a47xb01 | dsr b01(t+1) | MFMA a47xb23 | dsr b23(t+1)
#define TILE(T, AB, BB, ABn, BBn, STGA, STGB) do { \
  PH_BAR(); \
  LDS_A03(AB); \
  if (STGA) STAGE_A(ABn, ((T) + 1) * 64); \
  __builtin_amdgcn_s_setprio(1); MF(a03, b01, 0, 0); MF(a03, b23, 0, 2); __builtin_amdgcn_s_setprio(0); \
  VMC0M(); \
  PH_BAR(); \
  LDS_A47(AB); \
  if (STGB) STAGE_B(BB, ((T) + 2) * 64); \
  __builtin_amdgcn_s_setprio(1); MF(a47, b01, 4, 0); __builtin_amdgcn_s_setprio(0); \
  LDS_B01(BBn); \
  __builtin_amdgcn_s_setprio(1); MF(a47, b23, 4, 2); __builtin_amdgcn_s_setprio(0); \
  LDS_B23(BBn); \
} while (0)

#define TILE_LAST(AB, BB) do { \
  PH_BAR(); \
  LDS_A03(AB); \
  __builtin_amdgcn_s_setprio(1); MF(a03, b01, 0, 0); MF(a03, b23, 0, 2); __builtin_amdgcn_s_setprio(0); \
  PH_BAR(); \
  LDS_A47(AB); \
  __builtin_amdgcn_s_setprio(1); MF(a47, b01, 4, 0); MF(a47, b23, 4, 2); __builtin_amdgcn_s_setprio(0); \
} while (0)

// ---------------- weight transpose + fp32->bf16 ----------------
__global__ __launch_bounds__(256) void transpose_bf16_kernel(
    const float* __restrict__ in, __hip_bfloat16* __restrict__ outp, int R, int C)
{
  __shared__ float tile[32][33];
  const int c0 = blockIdx.x * 32, r0 = blockIdx.y * 32;
  const size_t eoff = (size_t)blockIdx.z * (size_t)R * (size_t)C;
  const float* ip = in + eoff;
  __hip_bfloat16* op = outp + eoff;
  const int tx = threadIdx.x, ty = threadIdx.y;
#pragma unroll
  for (int i = 0; i < 4; i++) {
    int r = ty + i * 8;
    tile[r][tx] = ip[(size_t)(r0 + r) * C + c0 + tx];
  }
  __syncthreads();
#pragma unroll
  for (int i = 0; i < 4; i++) {
    int c = ty + i * 8;
    op[(size_t)(c0 + c) * R + r0 + tx] = __float2bfloat16(tile[tx][c]);
  }
}

// ---------------- router ----------------
__global__ __launch_bounds__(256) void router_kernel(
    const float* __restrict__ x, const float* __restrict__ gw, const float* __restrict__ bias,
    float* __restrict__ scores, __hip_bfloat16* __restrict__ xb)
{
  __shared__ float g[E_EXP * DDIM];
  __shared__ float bs[E_EXP];
  const int tid = threadIdx.x;
  for (int i = tid; i < E_EXP * DDIM; i += 256) g[i] = gw[i];
  if (tid < E_EXP) bs[tid] = bias[tid];
  __syncthreads();
  const int w = tid >> 6, lane = tid & 63;
  const int s = blockIdx.x * 4 + w;
  double acc[E_EXP] = {0, 0, 0, 0, 0, 0, 0, 0};
  const float* xrow = x + (size_t)s * DDIM;
  __hip_bfloat16* xbrow = xb + (size_t)s * DDIM;
#pragma unroll 4
  for (int j = 0; j < 16; j++) {
    int d = lane + 64 * j;
    float xv = xrow[d];
    xbrow[d] = __float2bfloat16(xv);
#pragma unroll
    for (int e = 0; e < E_EXP; e++) acc[e] += (double)xv * (double)g[e * DDIM + d];
  }
#pragma unroll
  for (int e = 0; e < E_EXP; e++) {
    double a = acc[e];
#pragma unroll
    for (int off = 32; off > 0; off >>= 1) a += __shfl_xor(a, off);
    acc[e] = a;
  }
  if (lane == 0) {
#pragma unroll
    for (int e = 0; e < E_EXP; e++) {
      double lg = acc[e] + (double)bs[e];
      float sc = (float)(1.0 / (1.0 + exp(-lg)));
      scores[(size_t)e * S_TOK + s] = sc;
    }
  }
}

// ---------------- radix-8 select ----------------
__global__ __launch_bounds__(256) void hist_pass_kernel(
    const float* __restrict__ scores, const unsigned* __restrict__ meta,
    unsigned* __restrict__ hist, int pass)
{
  __shared__ unsigned h[256];
  const int tid = threadIdx.x;
  h[tid] = 0;
  __syncthreads();
  const unsigned prefix = meta[0];
  const int pshift = 32 - 8 * pass;
  const int bshift = 24 - 8 * pass;
  const unsigned base = blockIdx.x * 2048 + tid;
#pragma unroll
  for (int i = 0; i < 8; i++) {
    unsigned b = __float_as_uint(scores[base + i * 256]);
    bool ok = (pass == 0) || ((b >> pshift) == prefix);
    if (ok) atomicAdd(&h[(b >> bshift) & 0xFFu], 1u);
  }
  __syncthreads();
  if (h[tid]) atomicAdd(&hist[tid], h[tid]);
}

__global__ __launch_bounds__(256) void scan_pass_kernel(
    const unsigned* __restrict__ hist, unsigned* __restrict__ meta, int final)
{
  const int t = threadIdx.x;
  const unsigned v = hist[t];
  const unsigned prefix = meta[0];
  const unsigned above = meta[1];
  __shared__ unsigned csum[256];
  csum[t] = v;
  __syncthreads();
  for (int off = 1; off < 256; off <<= 1) {
    unsigned add = (t + off < 256) ? csum[t + off] : 0u;
    __syncthreads();
    csum[t] += add;
    __syncthreads();
  }
  const unsigned cge = csum[t];
  const unsigned cgt = cge - v;
  if (above + cgt < K_SEL && above + cge >= K_SEL) {
    meta[0] = (prefix << 8) | (unsigned)t;
    meta[1] = above + cgt;
    if (final) {
      meta[2] = (prefix << 8) | (unsigned)t;
      meta[4] = K_SEL - (above + cgt);
    }
  }
}

__global__ __launch_bounds__(256) void sel_kernel(const float* __restrict__ scores,
                                                  unsigned* __restrict__ meta,
                                                  unsigned* __restrict__ counts,
                                                  int* __restrict__ tok_list,
                                                  float* __restrict__ coef_list,
                                                  unsigned* __restrict__ tie_idx,
                                                  unsigned* __restrict__ tcnt,
                                                  unsigned* __restrict__ tslot)
{
  __shared__ unsigned lcnt[E_EXP], lbase[E_EXP];
  const int tid = threadIdx.x;
  if (tid < E_EXP) lcnt[tid] = 0;
  __syncthreads();
  const unsigned i = blockIdx.x * 256 + tid;
  const float v = scores[i];
  const unsigned b = __float_as_uint(v);
  const unsigned t = meta[2];
  const bool sel = (b > t);
  const unsigned e = i >> 14;
  unsigned myslot = 0;
  if (sel) myslot = atomicAdd(&lcnt[e], 1u);
  else if (b == t) {
    unsigned ts = atomicAdd(&meta[5], 1u);
    if (ts < 8192u) tie_idx[ts] = i;
  }
  __syncthreads();
  if (tid < E_EXP) lbase[tid] = atomicAdd(&counts[tid], lcnt[tid]);
  __syncthreads();
  if (sel) {
    const unsigned slot = lbase[e] + myslot;
    const unsigned p = e * S_TOK + slot;
    const unsigned tok = i & 16383u;
    tok_list[p] = (int)tok;
    coef_list[p] = v;
    unsigned us = atomicAdd(&tcnt[tok], 1u);
    tslot[tok * 8u + us] = (e << 14) | slot;
  }
}

__global__ __launch_bounds__(256) void fin_kernel(const unsigned* __restrict__ meta,
                                                  const unsigned* __restrict__ tie_idx,
                                                  unsigned* __restrict__ counts,
                                                  int* __restrict__ tok_list,
                                                  float* __restrict__ coef_list,
                                                  unsigned* __restrict__ tcnt,
                                                  unsigned* __restrict__ tslot)
{
  unsigned tcnt_ties = meta[5]; if (tcnt_ties > 8192u) tcnt_ties = 8192u;
  const unsigned q = meta[4];
  const float tval = __uint_as_float(meta[2]);
  for (unsigned t = threadIdx.x; t < tcnt_ties; t += 256) {
    unsigned idx = tie_idx[t];
    unsigned rank = 0;
    for (unsigned u = 0; u < tcnt_ties; u++) rank += (tie_idx[u] < idx) ? 1u : 0u;
    if (rank < q) {
      const unsigned e = idx >> 14;
      const unsigned tok = idx & 16383u;
      const unsigned slot = atomicAdd(&counts[e], 1u);
      tok_list[e * S_TOK + slot] = (int)tok;
      coef_list[e * S_TOK + slot] = tval;
      unsigned us = atomicAdd(&tcnt[tok], 1u);
      tslot[tok * 8u + us] = (e << 14) | slot;
    }
  }
}

__global__ void tail_kernel(const unsigned* __restrict__ counts, unsigned* __restrict__ exoff,
                            float* __restrict__ tail)
{
  if (threadIdx.x == 0) {
    unsigned o = 0;
    for (int e = 0; e < E_EXP; e++) { exoff[e] = o; o += counts[e]; }
    exoff[E_EXP] = o;
  }
  if (threadIdx.x < E_EXP) {
    tail[threadIdx.x] = (float)counts[threadIdx.x] * (1.0f / (float)K_SEL);
    tail[E_EXP + threadIdx.x] = 1.0f;
  }
}

// ---------------- GEMM1: hbuf = gelu(Xg @ W1 + b1), 256^2 2-phase ----------------
__global__ __launch_bounds__(512, 1) void gemm1_kernel(
    const __hip_bfloat16* __restrict__ xb,      // [S][D]
    const __hip_bfloat16* __restrict__ w1t,     // [E][H][D]
    const float* __restrict__ b1,               // [E][H]
    const int* __restrict__ tok_list,           // [E][S]
    const unsigned* __restrict__ counts,
    const unsigned* __restrict__ exoff,
    __hip_bfloat16* __restrict__ hbuf)          // [K_SEL][H]
{
  const int e = blockIdx.z;
  const int cnt = (int)counts[e];
  const int m0 = blockIdx.y * 256;
  if (m0 >= cnt) return;
  const int n0 = blockIdx.x * 256;

  __shared__ __align__(16) char lds[131072];
  __shared__ int s_tok[256];

  const int tid = threadIdx.x;
  const int w = tid >> 6, lane = tid & 63;
  const int wm = w >> 2, wn = w & 3;

  if (tid < 256) {
    int mi = m0 + tid;
    s_tok[tid] = tok_list[e * S_TOK + (mi < cnt ? mi : cnt - 1)];
  }
  __syncthreads();

  // stage-side per-thread pointers (pre-swizzled global chunk)
  const int srl0 = w * 16 + (lane >> 3);
  const int srl1 = srl0 + 8;
  const int gch = ((lane & 7) ^ (lane >> 3)) * 8;   // elems
  const __hip_bfloat16* aS00 = xb + (size_t)s_tok[srl0] * DDIM + gch;
  const __hip_bfloat16* aS01 = xb + (size_t)s_tok[srl1] * DDIM + gch;
  const __hip_bfloat16* aS10 = xb + (size_t)s_tok[128 + srl0] * DDIM + gch;
  const __hip_bfloat16* aS11 = xb + (size_t)s_tok[128 + srl1] * DDIM + gch;
  const __hip_bfloat16* w1e = w1t + (size_t)e * HDIM * DDIM;
  const __hip_bfloat16* bS00 = w1e + (size_t)(n0 + srl0) * DDIM + gch;
  const __hip_bfloat16* bS01 = w1e + (size_t)(n0 + srl1) * DDIM + gch;
  const __hip_bfloat16* bS10 = w1e + (size_t)(n0 + 128 + srl0) * DDIM + gch;
  const __hip_bfloat16* bS11 = w1e + (size_t)(n0 + 128 + srl1) * DDIM + gch;

  // read-side constants
  const int arow = (wm * 128 + (lane & 15)) * 128;  // bytes
  const int brow = (wn * 64 + (lane & 15)) * 128;
  const int pc0 = (((lane >> 4)) ^ (lane & 7)) * 16;
  const int pc1 = (((lane >> 4) + 4) ^ (lane & 7)) * 16;

  f32x4 acc[8][4] = {};
  bf16x8 a03[4][2], a47[4][2], b01[2][2], b23[2][2];

  // prologue: stage t0 A+B and t1 B; then pre-read t0's B fragments
  STAGE_A(ABUF0, 0);
  STAGE_B(BBUF0, 0);
  STAGE_B(BBUF1, 64);
  VMC0M();
  PH_BAR();
  LDS_B01(BBUF0); LDS_B23(BBUF0);

  const int NKT = DDIM / 64;  // 16
  int kt = 0;
  for (; kt + 2 < NKT; kt += 2) {
    TILE(kt,     ABUF0, BBUF0, ABUF1, BBUF1, true, true);
    TILE(kt + 1, ABUF1, BBUF1, ABUF0, BBUF0, true, true);
  }
  TILE(kt, ABUF0, BBUF0, ABUF1, BBUF1, true, false);  // kt = NKT-2
  TILE_LAST(ABUF1, BBUF1);                            // kt+1 = NKT-1
  __syncthreads();

  // ---- epilogue: gelu + LDS repack -> coalesced stores ----
  __hip_bfloat16* stg = (__hip_bfloat16*)lds;
  const float* b1e = b1 + (size_t)e * HDIM;
  float bvj[4];
#pragma unroll
  for (int j = 0; j < 4; j++) bvj[j] = b1e[n0 + wn * 64 + j * 16 + (lane & 15)];
  const int pbase = (int)exoff[e] + m0;

#pragma unroll
  for (int P = 0; P < 4; P++) {
    __syncthreads();
    if (wm == (P >> 1)) {
      const int ib = (P & 1) * 4;
#pragma unroll
      for (int ii = 0; ii < 4; ii++)
#pragma unroll
        for (int jj = 0; jj < 4; jj++)
#pragma unroll
          for (int r = 0; r < 4; r++) {
            const int rloc = ii * 16 + (lane >> 4) * 4 + r;
            const int col = wn * 64 + jj * 16 + (lane & 15);
            stg[rloc * 264 + col] = __float2bfloat16(gelu_f(acc[ib + ii][jj][r] + bvj[jj]));
          }
    }
    __syncthreads();
    const int rr = tid >> 3;
    const int m = P * 64 + rr;
    if (m0 + m < cnt) {
      __hip_bfloat16* dst = hbuf + (size_t)(pbase + m) * HDIM + n0;
      const __hip_bfloat16* src = stg + rr * 264;
#pragma unroll
      for (int c = 0; c < 4; c++)
        *(uint4*)(dst + (tid & 7) * 8 + c * 64) = *(const uint4*)(src + (tid & 7) * 8 + c * 64);
    }
  }
}

// ---------------- GEMM2: ybuf[slot] = coef * (H @ W2 + b2), 256^2 2-phase ----------------
__global__ __launch_bounds__(512, 1) void gemm2_kernel(
    const __hip_bfloat16* __restrict__ hbuf,    // [K_SEL][H]
    const __hip_bfloat16* __restrict__ w2t,     // [E][D][H]
    const float* __restrict__ b2,               // [E][D]
    const float* __restrict__ coef_list,
    const unsigned* __restrict__ counts,
    const unsigned* __restrict__ exoff,
    __hip_bfloat16* __restrict__ ybuf)          // [K_SEL][D]
{
  const int e = blockIdx.z;
  const int cnt = (int)counts[e];
  const int m0 = blockIdx.y * 256;
  if (m0 >= cnt) return;
  const int n0 = blockIdx.x * 256;

  __shared__ __align__(16) char lds[131072];
  __shared__ float s_coef[256];

  const int tid = threadIdx.x;
  const int w = tid >> 6, lane = tid & 63;
  const int wm = w >> 2, wn = w & 3;
  const int pb = (int)exoff[e];

  if (tid < 256) {
    int mi = m0 + tid;
    s_coef[tid] = (mi < cnt) ? coef_list[e * S_TOK + mi] : 0.0f;
  }
  __syncthreads();

  const int srl0 = w * 16 + (lane >> 3);
  const int srl1 = srl0 + 8;
  const int gch = ((lane & 7) ^ (lane >> 3)) * 8;
  const int ra0 = pb + ((m0 + srl0 < cnt) ? m0 + srl0 : cnt - 1);
  const int ra1 = pb + ((m0 + srl1 < cnt) ? m0 + srl1 : cnt - 1);
  const int ra2 = pb + ((m0 + 128 + srl0 < cnt) ? m0 + 128 + srl0 : cnt - 1);
  const int ra3 = pb + ((m0 + 128 + srl1 < cnt) ? m0 + 128 + srl1 : cnt - 1);
  const __hip_bfloat16* aS00 = hbuf + (size_t)ra0 * HDIM + gch;
  const __hip_bfloat16* aS01 = hbuf + (size_t)ra1 * HDIM + gch;
  const __hip_bfloat16* aS10 = hbuf + (size_t)ra2 * HDIM + gch;
  const __hip_bfloat16* aS11 = hbuf + (size_t)ra3 * HDIM + gch;
  const __hip_bfloat16* w2e = w2t + (size_t)e * DDIM * HDIM;
  const __hip_bfloat16* bS00 = w2e + (size_t)(n0 + srl0) * HDIM + gch;
  const __hip_bfloat16* bS01 = w2e + (size_t)(n0 + srl1) * HDIM + gch;
  const __hip_bfloat16* bS10 = w2e + (size_t)(n0 + 128 + srl0) * HDIM + gch;
  const __hip_bfloat16* bS11 = w2e + (size_t)(n0 + 128 + srl1) * HDIM + gch;

  const int arow = (wm * 128 + (lane & 15)) * 128;
  const int brow = (wn * 64 + (lane & 15)) * 128;
  const int pc0 = (((lane >> 4)) ^ (lane & 7)) * 16;
  const int pc1 = (((lane >> 4) + 4) ^ (lane & 7)) * 16;

  f32x4 acc[8][4] = {};
  bf16x8 a03[4][2], a47[4][2], b01[2][2], b23[2][2];

  STAGE_A(ABUF0, 0);
  STAGE_B(BBUF0, 0);
  STAGE_B(BBUF1, 64);
  VMC0M();
  PH_BAR();
  LDS_B01(BBUF0); LDS_B23(BBUF0);

  const int NKT = HDIM / 64;  // 64
  int kt = 0;
  for (; kt + 2 < NKT; kt += 2) {
    TILE(kt,     ABUF0, BBUF0, ABUF1, BBUF1, true, true);
    TILE(kt + 1, ABUF1, BBUF1, ABUF0, BBUF0, true, true);
  }
  TILE(kt, ABUF0, BBUF0, ABUF1, BBUF1, true, false);
  TILE_LAST(ABUF1, BBUF1);
  __syncthreads();

  // ---- epilogue: coef scale + LDS repack -> coalesced stores ----
  __hip_bfloat16* stg = (__hip_bfloat16*)lds;
  const float* b2e = b2 + (size_t)e * DDIM;
  float bvj[4];
#pragma unroll
  for (int j = 0; j < 4; j++) bvj[j] = b2e[n0 + wn * 64 + j * 16 + (lane & 15)];
  const int pbase = pb + m0;

#pragma unroll
  for (int P = 0; P < 4; P++) {
    __syncthreads();
    if (wm == (P >> 1)) {
      const int ib = (P & 1) * 4;
#pragma unroll
      for (int ii = 0; ii < 4; ii++)
#pragma unroll
        for (int jj = 0; jj < 4; jj++)
#pragma unroll
          for (int r = 0; r < 4; r++) {
            const int rloc = ii * 16 + (lane >> 4) * 4 + r;
            const int col = wn * 64 + jj * 16 + (lane & 15);
            const float cf = s_coef[P * 64 + rloc];
            stg[rloc * 264 + col] = __float2bfloat16(cf * (acc[ib + ii][jj][r] + bvj[jj]));
          }
    }
    __syncthreads();
    const int rr = tid >> 3;
    const int m = P * 64 + rr;
    if (m0 + m < cnt) {
      __hip_bfloat16* dst = ybuf + (size_t)(pbase + m) * DDIM + n0;
      const __hip_bfloat16* src = stg + rr * 264;
#pragma unroll
      for (int c = 0; c < 4; c++)
        *(uint4*)(dst + (tid & 7) * 8 + c * 64) = *(const uint4*)(src + (tid & 7) * 8 + c * 64);
    }
  }
}

// ---------------- combine ----------------
__global__ __launch_bounds__(256) void combine_kernel(
    const __hip_bfloat16* __restrict__ ybuf,    // [K_SEL][D]
    const unsigned* __restrict__ tcnt,
    const unsigned* __restrict__ tslot,
    const unsigned* __restrict__ exoff,
    float* __restrict__ out)                    // [S][D]
{
  const int tid = threadIdx.x;
  const int t = blockIdx.x * 2 + (tid >> 7);
  const int d0 = (tid & 127) * 8;
  float a[8] = {0, 0, 0, 0, 0, 0, 0, 0};
  const unsigned n = tcnt[t];
  for (unsigned s = 0; s < n; s++) {
    const unsigned code = tslot[t * 8u + s];
    const unsigned p = exoff[code >> 14] + (code & 16383u);
    bf16x8 v = *(const bf16x8*)(ybuf + (size_t)p * DDIM + d0);
#pragma unroll
    for (int k = 0; k < 8; k++)
      a[k] += __uint_as_float(((unsigned)(unsigned short)v[k]) << 16);
  }
  float* op = out + (size_t)t * DDIM + d0;
  *(float4*)op = make_float4(a[0], a[1], a[2], a[3]);
  *(float4*)(op + 4) = make_float4(a[4], a[5], a[6], a[7]);
}

// ---------------- launch ----------------
extern "C" void kernel_launch(void* const* d_in, const int* in_sizes, int n_in,
                              void* d_out, int out_size, void* d_ws, size_t ws_size,
                              hipStream_t stream) {
  const float* x    = (const float*)d_in[0];
  const float* gw   = (const float*)d_in[1];
  const float* bias = (const float*)d_in[2];
  const float* W1   = (const float*)d_in[3];
  const float* b1   = (const float*)d_in[4];
  const float* W2   = (const float*)d_in[5];
  const float* b2   = (const float*)d_in[6];
  float* out = (float*)d_out;
  char* ws = (char*)d_ws;

  if (ws_size < (size_t)WS_TOTAL) {
    fprintf(stderr, "kernel_launch: ws_size %zu < required %u\n", ws_size, WS_TOTAL);
    return;
  }

  unsigned* meta   = (unsigned*)(ws + WS_META);
  unsigned* hist   = (unsigned*)(ws + WS_HIST);
  unsigned* counts = (unsigned*)(ws + WS_COUNTS);
  unsigned* exoff  = (unsigned*)(ws + WS_EXOFF);
  unsigned* tiei   = (unsigned*)(ws + WS_TIEIDX);
  unsigned* tcnt   = (unsigned*)(ws + WS_TCNT);
  unsigned* tslot  = (unsigned*)(ws + WS_TSLOT);
  int*      tokl   = (int*)(ws + WS_TOK);
  float*    coefl  = (float*)(ws + WS_COEF);
  float*    scores = (float*)(ws + WS_SCORES);
  __hip_bfloat16* xb   = (__hip_bfloat16*)(ws + WS_XB);
  __hip_bfloat16* w1t  = (__hip_bfloat16*)(ws + WS_W1T);
  __hip_bfloat16* w2t  = (__hip_bfloat16*)(ws + WS_W2T);
  __hip_bfloat16* hbuf = (__hip_bfloat16*)(ws + WS_HBUF);
  __hip_bfloat16* ybuf = (__hip_bfloat16*)(ws + WS_YBUF);

  hipMemsetAsync(ws, 0, WS_CLEAR, stream);
  hipMemsetAsync(ws + WS_TCNT, 0, S_TOK * sizeof(unsigned), stream);

  transpose_bf16_kernel<<<dim3(HDIM / 32, DDIM / 32, E_EXP), dim3(32, 8), 0, stream>>>(W1, w1t, DDIM, HDIM);
  transpose_bf16_kernel<<<dim3(DDIM / 32, HDIM / 32, E_EXP), dim3(32, 8), 0, stream>>>(W2, w2t, HDIM, DDIM);

  router_kernel<<<S_TOK / 4, 256, 0, stream>>>(x, gw, bias, scores, xb);

  for (int p = 0; p < 4; p++) {
    hist_pass_kernel<<<ES / 2048, 256, 0, stream>>>(scores, meta, hist + p * 256, p);
    scan_pass_kernel<<<1, 256, 0, stream>>>(hist + p * 256, meta, p == 3);
  }
  sel_kernel<<<ES / 256, 256, 0, stream>>>(scores, meta, counts, tokl, coefl, tiei, tcnt, tslot);
  fin_kernel<<<1, 256, 0, stream>>>(meta, tiei, counts, tokl, coefl, tcnt, tslot);
  tail_kernel<<<1, 64, 0, stream>>>(counts, exoff, out + OUT_XO);

  gemm1_kernel<<<dim3(HDIM / 256, S_TOK / 256, E_EXP), 512, 0, stream>>>(
      xb, w1t, b1, tokl, counts, exoff, hbuf);
  gemm2_kernel<<<dim3(DDIM / 256, S_TOK / 256, E_EXP), 512, 0, stream>>>(
      hbuf, w2t, b2, coefl, counts, exoff, ybuf);
  combine_kernel<<<S_TOK / 2, 256, 0, stream>>>(ybuf, tcnt, tslot, exoff, out);
}

// Round 6
// 860.129 us; speedup vs baseline: 2.3983x; 1.1010x over previous
//
#include <hip/hip_runtime.h>
#include <hip/hip_bf16.h>
#include <cstdint>
#include <cstdio>
#include <math.h>

// ---------------- problem constants ----------------
#define S_TOK 16384     // B*SEQ
#define E_EXP 8
#define DDIM  1024
#define HDIM  4096
#define K_SEL 32768     // int(S * 2.0)
#define ES    131072    // E * S
#define OUT_XO 16777216 // S*D

// ---------------- workspace layout (bytes) ----------------
#define WS_META    0x000000u   // 16 u32
#define WS_HIST    0x000100u   // 4 passes x 256 u32
#define WS_COUNTS  0x001100u   // 8 u32
#define WS_EXOFF   0x001200u   // 9 u32
#define WS_TIEIDX  0x001300u   // 8192 u32
#define WS_CLEAR   0x00A000u
#define WS_TOK     0x010000u   // E*S int
#define WS_COEF    0x090000u   // E*S float
#define WS_SCORES  0x110000u   // E*S float
#define WS_TCNT    0x190000u   // S u32
#define WS_TSLOT   0x1A0000u   // S*8 u32
#define WS_XB      0x400000u   // S*D bf16 (32MB)
#define WS_W1T    0x2400000u   // E*H*D bf16 (64MB)  [aliased as ybuf after gemm1]
#define WS_W2T    0x6400000u   // E*D*H bf16 (64MB)
#define WS_HBUF   0xA400000u   // K_SEL*H bf16 (256MB)
#define WS_TOTAL  0x1A400000u
#define WS_YBUF   WS_W1T

typedef __attribute__((ext_vector_type(4))) float f32x4;
typedef __attribute__((ext_vector_type(8))) short bf16x8;

__device__ __forceinline__ void gload_lds16(const void* g, void* l) {
  __builtin_amdgcn_global_load_lds((const __attribute__((address_space(1))) void*)g,
                                   (__attribute__((address_space(3))) void*)l, 16, 0, 0);
}

__device__ __forceinline__ float gelu_f(float x) {
  float u = __builtin_fmaf(x * x * x, 0.044715f, x);
  float e = __builtin_amdgcn_exp2f(-2.302207976f * u);
  return x * __builtin_amdgcn_rcpf(1.0f + e);
}

// ================= 2-phase/tile 256^2 GEMM machinery =================
// LDS: A buf0 @0, A buf1 @32768, B buf0 @65536, B buf1 @98304; halves +16384.
// Swizzle: 16B chunk c of a 128B row r holds logical chunk c ^ (r&7);
// stage side pre-swizzles the GLOBAL source chunk, LDS dest stays linear.
#define ABUF0 0
#define ABUF1 32768
#define BBUF0 65536
#define BBUF1 98304
#define HALF  16384

#define PH_BAR() __builtin_amdgcn_s_barrier()
#define VMC0M()  asm volatile("s_waitcnt vmcnt(0)" ::: "memory")
// counted waits (T4): never 0 in steady state; "memory" orders vs LDS/staging ops
#define VMCN(N)  asm volatile("s_waitcnt vmcnt(" #N ")" ::: "memory")

// stage one full 256-row tile half-pair (4 gloads: h0 rows, h1 rows)
#define STAGE_A(DST, KE) do { \
  gload_lds16(aS00 + (KE), lds + (DST) + w * 2048); \
  gload_lds16(aS01 + (KE), lds + (DST) + w * 2048 + 1024); \
  gload_lds16(aS10 + (KE), lds + (DST) + HALF + w * 2048); \
  gload_lds16(aS11 + (KE), lds + (DST) + HALF + w * 2048 + 1024); } while (0)
#define STAGE_B(DST, KE) do { \
  gload_lds16(bS00 + (KE), lds + (DST) + w * 2048); \
  gload_lds16(bS01 + (KE), lds + (DST) + w * 2048 + 1024); \
  gload_lds16(bS10 + (KE), lds + (DST) + HALF + w * 2048); \
  gload_lds16(bS11 + (KE), lds + (DST) + HALF + w * 2048 + 1024); } while (0)

#define LDS_A03(AB) { _Pragma("unroll") for (int ii = 0; ii < 4; ii++) { \
  a03[ii][0] = *(const bf16x8*)(lds + (AB) + arow + ii * 2048 + pc0); \
  a03[ii][1] = *(const bf16x8*)(lds + (AB) + arow + ii * 2048 + pc1); } }
#define LDS_A47(AB) { _Pragma("unroll") for (int ii = 0; ii < 4; ii++) { \
  a47[ii][0] = *(const bf16x8*)(lds + (AB) + arow + (4 + ii) * 2048 + pc0); \
  a47[ii][1] = *(const bf16x8*)(lds + (AB) + arow + (4 + ii) * 2048 + pc1); } }
#define LDS_B01(BB) { _Pragma("unroll") for (int jj = 0; jj < 2; jj++) { \
  b01[jj][0] = *(const bf16x8*)(lds + (BB) + brow + jj * 2048 + pc0); \
  b01[jj][1] = *(const bf16x8*)(lds + (BB) + brow + jj * 2048 + pc1); } }
#define LDS_B23(BB) { _Pragma("unroll") for (int jj = 0; jj < 2; jj++) { \
  b23[jj][0] = *(const bf16x8*)(lds + (BB) + brow + (2 + jj) * 2048 + pc0); \
  b23[jj][1] = *(const bf16x8*)(lds + (BB) + brow + (2 + jj) * 2048 + pc1); } }

#define MF(AA, BF, IL, JL) { _Pragma("unroll") for (int ii = 0; ii < 4; ii++) \
  _Pragma("unroll") for (int jj = 0; jj < 2; jj++) { \
    acc[(IL)+ii][(JL)+jj] = __builtin_amdgcn_mfma_f32_16x16x32_bf16(AA[ii][0], BF[jj][0], acc[(IL)+ii][(JL)+jj], 0, 0, 0); \
    acc[(IL)+ii][(JL)+jj] = __builtin_amdgcn_mfma_f32_16x16x32_bf16(AA[ii][1], BF[jj][1], acc[(IL)+ii][(JL)+jj], 0, 0, 0); } }

// One K-tile, 2 phases, per-wave load FIFO: [.., A(t+1)@P0, B(t+2)@P1, ..]
//   P0: bar | dsr A03(t) | stage A(t+1) | MFMA a03xB            (no waits)
//   P1: bar | dsr A47(t) | stage B(t+2) | MFMA a47xb01 | vmcnt(NB) -> B(t+1) landed
//       | dsr b01(t+1) | MFMA a47xb23 | dsr b23(t+1) | vmcnt(NA) -> A(t+1) landed
#define TILE(T, AB, BB, ABn, BBn, STGA, STGB, NB, NA) do { \
  PH_BAR(); \
  LDS_A03(AB); \
  if (STGA) STAGE_A(ABn, ((T) + 1) * 64); \
  __builtin_amdgcn_s_setprio(1); MF(a03, b01, 0, 0); MF(a03, b23, 0, 2); __builtin_amdgcn_s_setprio(0); \
  PH_BAR(); \
  LDS_A47(AB); \
  if (STGB) STAGE_B(BB, ((T) + 2) * 64); \
  __builtin_amdgcn_s_setprio(1); MF(a47, b01, 4, 0); __builtin_amdgcn_s_setprio(0); \
  VMCN(NB); \
  LDS_B01(BBn); \
  __builtin_amdgcn_s_setprio(1); MF(a47, b23, 4, 2); __builtin_amdgcn_s_setprio(0); \
  LDS_B23(BBn); \
  VMCN(NA); \
} while (0)

#define TILE_LAST(AB, BB) do { \
  PH_BAR(); \
  LDS_A03(AB); \
  __builtin_amdgcn_s_setprio(1); MF(a03, b01, 0, 0); MF(a03, b23, 0, 2); __builtin_amdgcn_s_setprio(0); \
  PH_BAR(); \
  LDS_A47(AB); \
  __builtin_amdgcn_s_setprio(1); MF(a47, b01, 4, 0); MF(a47, b23, 4, 2); __builtin_amdgcn_s_setprio(0); \
} while (0)

// ---------------- weight transpose + fp32->bf16 ----------------
__global__ __launch_bounds__(256) void transpose_bf16_kernel(
    const float* __restrict__ in, __hip_bfloat16* __restrict__ outp, int R, int C)
{
  __shared__ float tile[32][33];
  const int c0 = blockIdx.x * 32, r0 = blockIdx.y * 32;
  const size_t eoff = (size_t)blockIdx.z * (size_t)R * (size_t)C;
  const float* ip = in + eoff;
  __hip_bfloat16* op = outp + eoff;
  const int tx = threadIdx.x, ty = threadIdx.y;
#pragma unroll
  for (int i = 0; i < 4; i++) {
    int r = ty + i * 8;
    tile[r][tx] = ip[(size_t)(r0 + r) * C + c0 + tx];
  }
  __syncthreads();
#pragma unroll
  for (int i = 0; i < 4; i++) {
    int c = ty + i * 8;
    op[(size_t)(c0 + c) * R + r0 + tx] = __float2bfloat16(tile[tx][c]);
  }
}

// ---------------- router ----------------
__global__ __launch_bounds__(256) void router_kernel(
    const float* __restrict__ x, const float* __restrict__ gw, const float* __restrict__ bias,
    float* __restrict__ scores, __hip_bfloat16* __restrict__ xb)
{
  __shared__ float g[E_EXP * DDIM];
  __shared__ float bs[E_EXP];
  const int tid = threadIdx.x;
  for (int i = tid; i < E_EXP * DDIM; i += 256) g[i] = gw[i];
  if (tid < E_EXP) bs[tid] = bias[tid];
  __syncthreads();
  const int w = tid >> 6, lane = tid & 63;
  const int s = blockIdx.x * 4 + w;
  double acc[E_EXP] = {0, 0, 0, 0, 0, 0, 0, 0};
  const float* xrow = x + (size_t)s * DDIM;
  __hip_bfloat16* xbrow = xb + (size_t)s * DDIM;
#pragma unroll 4
  for (int j = 0; j < 16; j++) {
    int d = lane + 64 * j;
    float xv = xrow[d];
    xbrow[d] = __float2bfloat16(xv);
#pragma unroll
    for (int e = 0; e < E_EXP; e++) acc[e] += (double)xv * (double)g[e * DDIM + d];
  }
#pragma unroll
  for (int e = 0; e < E_EXP; e++) {
    double a = acc[e];
#pragma unroll
    for (int off = 32; off > 0; off >>= 1) a += __shfl_xor(a, off);
    acc[e] = a;
  }
  if (lane == 0) {
#pragma unroll
    for (int e = 0; e < E_EXP; e++) {
      double lg = acc[e] + (double)bs[e];
      float sc = (float)(1.0 / (1.0 + exp(-lg)));
      scores[(size_t)e * S_TOK + s] = sc;
    }
  }
}

// ---------------- radix-8 select ----------------
__global__ __launch_bounds__(256) void hist_pass_kernel(
    const float* __restrict__ scores, const unsigned* __restrict__ meta,
    unsigned* __restrict__ hist, int pass)
{
  __shared__ unsigned h[256];
  const int tid = threadIdx.x;
  h[tid] = 0;
  __syncthreads();
  const unsigned prefix = meta[0];
  const int pshift = 32 - 8 * pass;
  const int bshift = 24 - 8 * pass;
  const unsigned base = blockIdx.x * 2048 + tid;
#pragma unroll
  for (int i = 0; i < 8; i++) {
    unsigned b = __float_as_uint(scores[base + i * 256]);
    bool ok = (pass == 0) || ((b >> pshift) == prefix);
    if (ok) atomicAdd(&h[(b >> bshift) & 0xFFu], 1u);
  }
  __syncthreads();
  if (h[tid]) atomicAdd(&hist[tid], h[tid]);
}

__global__ __launch_bounds__(256) void scan_pass_kernel(
    const unsigned* __restrict__ hist, unsigned* __restrict__ meta, int final)
{
  const int t = threadIdx.x;
  const unsigned v = hist[t];
  const unsigned prefix = meta[0];
  const unsigned above = meta[1];
  __shared__ unsigned csum[256];
  csum[t] = v;
  __syncthreads();
  for (int off = 1; off < 256; off <<= 1) {
    unsigned add = (t + off < 256) ? csum[t + off] : 0u;
    __syncthreads();
    csum[t] += add;
    __syncthreads();
  }
  const unsigned cge = csum[t];
  const unsigned cgt = cge - v;
  if (above + cgt < K_SEL && above + cge >= K_SEL) {
    meta[0] = (prefix << 8) | (unsigned)t;
    meta[1] = above + cgt;
    if (final) {
      meta[2] = (prefix << 8) | (unsigned)t;
      meta[4] = K_SEL - (above + cgt);
    }
  }
}

__global__ __launch_bounds__(256) void sel_kernel(const float* __restrict__ scores,
                                                  unsigned* __restrict__ meta,
                                                  unsigned* __restrict__ counts,
                                                  int* __restrict__ tok_list,
                                                  float* __restrict__ coef_list,
                                                  unsigned* __restrict__ tie_idx,
                                                  unsigned* __restrict__ tcnt,
                                                  unsigned* __restrict__ tslot)
{
  __shared__ unsigned lcnt[E_EXP], lbase[E_EXP];
  const int tid = threadIdx.x;
  if (tid < E_EXP) lcnt[tid] = 0;
  __syncthreads();
  const unsigned i = blockIdx.x * 256 + tid;
  const float v = scores[i];
  const unsigned b = __float_as_uint(v);
  const unsigned t = meta[2];
  const bool sel = (b > t);
  const unsigned e = i >> 14;
  unsigned myslot = 0;
  if (sel) myslot = atomicAdd(&lcnt[e], 1u);
  else if (b == t) {
    unsigned ts = atomicAdd(&meta[5], 1u);
    if (ts < 8192u) tie_idx[ts] = i;
  }
  __syncthreads();
  if (tid < E_EXP) lbase[tid] = atomicAdd(&counts[tid], lcnt[tid]);
  __syncthreads();
  if (sel) {
    const unsigned slot = lbase[e] + myslot;
    const unsigned p = e * S_TOK + slot;
    const unsigned tok = i & 16383u;
    tok_list[p] = (int)tok;
    coef_list[p] = v;
    unsigned us = atomicAdd(&tcnt[tok], 1u);
    tslot[tok * 8u + us] = (e << 14) | slot;
  }
}

__global__ __launch_bounds__(256) void fin_kernel(const unsigned* __restrict__ meta,
                                                  const unsigned* __restrict__ tie_idx,
                                                  unsigned* __restrict__ counts,
                                                  int* __restrict__ tok_list,
                                                  float* __restrict__ coef_list,
                                                  unsigned* __restrict__ tcnt,
                                                  unsigned* __restrict__ tslot)
{
  unsigned tcnt_ties = meta[5]; if (tcnt_ties > 8192u) tcnt_ties = 8192u;
  const unsigned q = meta[4];
  const float tval = __uint_as_float(meta[2]);
  for (unsigned t = threadIdx.x; t < tcnt_ties; t += 256) {
    unsigned idx = tie_idx[t];
    unsigned rank = 0;
    for (unsigned u = 0; u < tcnt_ties; u++) rank += (tie_idx[u] < idx) ? 1u : 0u;
    if (rank < q) {
      const unsigned e = idx >> 14;
      const unsigned tok = idx & 16383u;
      const unsigned slot = atomicAdd(&counts[e], 1u);
      tok_list[e * S_TOK + slot] = (int)tok;
      coef_list[e * S_TOK + slot] = tval;
      unsigned us = atomicAdd(&tcnt[tok], 1u);
      tslot[tok * 8u + us] = (e << 14) | slot;
    }
  }
}

__global__ void tail_kernel(const unsigned* __restrict__ counts, unsigned* __restrict__ exoff,
                            float* __restrict__ tail)
{
  if (threadIdx.x == 0) {
    unsigned o = 0;
    for (int e = 0; e < E_EXP; e++) { exoff[e] = o; o += counts[e]; }
    exoff[E_EXP] = o;
  }
  if (threadIdx.x < E_EXP) {
    tail[threadIdx.x] = (float)counts[threadIdx.x] * (1.0f / (float)K_SEL);
    tail[E_EXP + threadIdx.x] = 1.0f;
  }
}

// ---------------- GEMM1: hbuf = gelu(Xg @ W1 + b1), 256^2 2-phase ----------------
// 1D grid 8192 blocks; XCD-chunked bijective swizzle; logical order e-major, y, x-fastest
__global__ __launch_bounds__(512, 1) void gemm1_kernel(
    const __hip_bfloat16* __restrict__ xb,      // [S][D]
    const __hip_bfloat16* __restrict__ w1t,     // [E][H][D]
    const float* __restrict__ b1,               // [E][H]
    const int* __restrict__ tok_list,           // [E][S]
    const unsigned* __restrict__ counts,
    const unsigned* __restrict__ exoff,
    __hip_bfloat16* __restrict__ hbuf)          // [K_SEL][H]
{
  const int id = blockIdx.x;
  const int L = (id & 7) * 1024 + (id >> 3);    // nwg=8192, chunk=1024 (one expert per XCD)
  const int e = L >> 10;
  const int rem = L & 1023;
  const int cnt = (int)counts[e];
  const int m0 = (rem >> 4) * 256;
  if (m0 >= cnt) return;
  const int n0 = (rem & 15) * 256;

  __shared__ __align__(16) char lds[131072];
  __shared__ int s_tok[256];

  const int tid = threadIdx.x;
  const int w = tid >> 6, lane = tid & 63;
  const int wm = w >> 2, wn = w & 3;

  if (tid < 256) {
    int mi = m0 + tid;
    s_tok[tid] = tok_list[e * S_TOK + (mi < cnt ? mi : cnt - 1)];
  }
  __syncthreads();

  // stage-side per-thread pointers (pre-swizzled global chunk)
  const int srl0 = w * 16 + (lane >> 3);
  const int srl1 = srl0 + 8;
  const int gch = ((lane & 7) ^ (lane >> 3)) * 8;   // elems
  const __hip_bfloat16* aS00 = xb + (size_t)s_tok[srl0] * DDIM + gch;
  const __hip_bfloat16* aS01 = xb + (size_t)s_tok[srl1] * DDIM + gch;
  const __hip_bfloat16* aS10 = xb + (size_t)s_tok[128 + srl0] * DDIM + gch;
  const __hip_bfloat16* aS11 = xb + (size_t)s_tok[128 + srl1] * DDIM + gch;
  const __hip_bfloat16* w1e = w1t + (size_t)e * HDIM * DDIM;
  const __hip_bfloat16* bS00 = w1e + (size_t)(n0 + srl0) * DDIM + gch;
  const __hip_bfloat16* bS01 = w1e + (size_t)(n0 + srl1) * DDIM + gch;
  const __hip_bfloat16* bS10 = w1e + (size_t)(n0 + 128 + srl0) * DDIM + gch;
  const __hip_bfloat16* bS11 = w1e + (size_t)(n0 + 128 + srl1) * DDIM + gch;

  // read-side constants
  const int arow = (wm * 128 + (lane & 15)) * 128;  // bytes
  const int brow = (wn * 64 + (lane & 15)) * 128;
  const int pc0 = (((lane >> 4)) ^ (lane & 7)) * 16;
  const int pc1 = (((lane >> 4) + 4) ^ (lane & 7)) * 16;

  f32x4 acc[8][4] = {};
  bf16x8 a03[4][2], a47[4][2], b01[2][2], b23[2][2];

  // prologue: stage t0 A+B and t1 B; then pre-read t0's B fragments
  STAGE_A(ABUF0, 0);
  STAGE_B(BBUF0, 0);
  STAGE_B(BBUF1, 64);
  VMC0M();
  PH_BAR();
  LDS_B01(BBUF0); LDS_B23(BBUF0);

  const int NKT = DDIM / 64;  // 16
  int kt = 0;
  for (; kt + 2 < NKT; kt += 2) {
    TILE(kt,     ABUF0, BBUF0, ABUF1, BBUF1, true, true, 8, 4);
    TILE(kt + 1, ABUF1, BBUF1, ABUF0, BBUF0, true, true, 8, 4);
  }
  TILE(kt, ABUF0, BBUF0, ABUF1, BBUF1, true, false, 4, 0);  // penult
  TILE_LAST(ABUF1, BBUF1);
  __syncthreads();

  // ---- epilogue: gelu + LDS repack -> coalesced stores ----
  __hip_bfloat16* stg = (__hip_bfloat16*)lds;
  const float* b1e = b1 + (size_t)e * HDIM;
  float bvj[4];
#pragma unroll
  for (int j = 0; j < 4; j++) bvj[j] = b1e[n0 + wn * 64 + j * 16 + (lane & 15)];
  const int pbase = (int)exoff[e] + m0;

#pragma unroll
  for (int P = 0; P < 4; P++) {
    __syncthreads();
    if (wm == (P >> 1)) {
      const int ib = (P & 1) * 4;
#pragma unroll
      for (int ii = 0; ii < 4; ii++)
#pragma unroll
        for (int jj = 0; jj < 4; jj++)
#pragma unroll
          for (int r = 0; r < 4; r++) {
            const int rloc = ii * 16 + (lane >> 4) * 4 + r;
            const int col = wn * 64 + jj * 16 + (lane & 15);
            stg[rloc * 264 + col] = __float2bfloat16(gelu_f(acc[ib + ii][jj][r] + bvj[jj]));
          }
    }
    __syncthreads();
    const int rr = tid >> 3;
    const int m = P * 64 + rr;
    if (m0 + m < cnt) {
      __hip_bfloat16* dst = hbuf + (size_t)(pbase + m) * HDIM + n0;
      const __hip_bfloat16* src = stg + rr * 264;
#pragma unroll
      for (int c = 0; c < 4; c++)
        *(uint4*)(dst + (tid & 7) * 8 + c * 64) = *(const uint4*)(src + (tid & 7) * 8 + c * 64);
    }
  }
}

// ---------------- GEMM2: ybuf[slot] = coef * (H @ W2 + b2), 256^2 2-phase ----------------
__global__ __launch_bounds__(512, 1) void gemm2_kernel(
    const __hip_bfloat16* __restrict__ hbuf,    // [K_SEL][H]
    const __hip_bfloat16* __restrict__ w2t,     // [E][D][H]
    const float* __restrict__ b2,               // [E][D]
    const float* __restrict__ coef_list,
    const unsigned* __restrict__ counts,
    const unsigned* __restrict__ exoff,
    __hip_bfloat16* __restrict__ ybuf)          // [K_SEL][D]
{
  const int id = blockIdx.x;
  const int L = (id & 7) * 256 + (id >> 3);     // nwg=2048, chunk=256 (one expert per XCD)
  const int e = L >> 8;
  const int rem = L & 255;
  const int cnt = (int)counts[e];
  const int m0 = (rem >> 2) * 256;
  if (m0 >= cnt) return;
  const int n0 = (rem & 3) * 256;

  __shared__ __align__(16) char lds[131072];
  __shared__ float s_coef[256];

  const int tid = threadIdx.x;
  const int w = tid >> 6, lane = tid & 63;
  const int wm = w >> 2, wn = w & 3;
  const int pb = (int)exoff[e];

  if (tid < 256) {
    int mi = m0 + tid;
    s_coef[tid] = (mi < cnt) ? coef_list[e * S_TOK + mi] : 0.0f;
  }
  __syncthreads();

  const int srl0 = w * 16 + (lane >> 3);
  const int srl1 = srl0 + 8;
  const int gch = ((lane & 7) ^ (lane >> 3)) * 8;
  const int ra0 = pb + ((m0 + srl0 < cnt) ? m0 + srl0 : cnt - 1);
  const int ra1 = pb + ((m0 + srl1 < cnt) ? m0 + srl1 : cnt - 1);
  const int ra2 = pb + ((m0 + 128 + srl0 < cnt) ? m0 + 128 + srl0 : cnt - 1);
  const int ra3 = pb + ((m0 + 128 + srl1 < cnt) ? m0 + 128 + srl1 : cnt - 1);
  const __hip_bfloat16* aS00 = hbuf + (size_t)ra0 * HDIM + gch;
  const __hip_bfloat16* aS01 = hbuf + (size_t)ra1 * HDIM + gch;
  const __hip_bfloat16* aS10 = hbuf + (size_t)ra2 * HDIM + gch;
  const __hip_bfloat16* aS11 = hbuf + (size_t)ra3 * HDIM + gch;
  const __hip_bfloat16* w2e = w2t + (size_t)e * DDIM * HDIM;
  const __hip_bfloat16* bS00 = w2e + (size_t)(n0 + srl0) * HDIM + gch;
  const __hip_bfloat16* bS01 = w2e + (size_t)(n0 + srl1) * HDIM + gch;
  const __hip_bfloat16* bS10 = w2e + (size_t)(n0 + 128 + srl0) * HDIM + gch;
  const __hip_bfloat16* bS11 = w2e + (size_t)(n0 + 128 + srl1) * HDIM + gch;

  const int arow = (wm * 128 + (lane & 15)) * 128;
  const int brow = (wn * 64 + (lane & 15)) * 128;
  const int pc0 = (((lane >> 4)) ^ (lane & 7)) * 16;
  const int pc1 = (((lane >> 4) + 4) ^ (lane & 7)) * 16;

  f32x4 acc[8][4] = {};
  bf16x8 a03[4][2], a47[4][2], b01[2][2], b23[2][2];

  STAGE_A(ABUF0, 0);
  STAGE_B(BBUF0, 0);
  STAGE_B(BBUF1, 64);
  VMC0M();
  PH_BAR();
  LDS_B01(BBUF0); LDS_B23(BBUF0);

  const int NKT = HDIM / 64;  // 64
  int kt = 0;
  for (; kt + 2 < NKT; kt += 2) {
    TILE(kt,     ABUF0, BBUF0, ABUF1, BBUF1, true, true, 8, 4);
    TILE(kt + 1, ABUF1, BBUF1, ABUF0, BBUF0, true, true, 8, 4);
  }
  TILE(kt, ABUF0, BBUF0, ABUF1, BBUF1, true, false, 4, 0);
  TILE_LAST(ABUF1, BBUF1);
  __syncthreads();

  // ---- epilogue: coef scale + LDS repack -> coalesced stores ----
  __hip_bfloat16* stg = (__hip_bfloat16*)lds;
  const float* b2e = b2 + (size_t)e * DDIM;
  float bvj[4];
#pragma unroll
  for (int j = 0; j < 4; j++) bvj[j] = b2e[n0 + wn * 64 + j * 16 + (lane & 15)];
  const int pbase = pb + m0;

#pragma unroll
  for (int P = 0; P < 4; P++) {
    __syncthreads();
    if (wm == (P >> 1)) {
      const int ib = (P & 1) * 4;
#pragma unroll
      for (int ii = 0; ii < 4; ii++)
#pragma unroll
        for (int jj = 0; jj < 4; jj++)
#pragma unroll
          for (int r = 0; r < 4; r++) {
            const int rloc = ii * 16 + (lane >> 4) * 4 + r;
            const int col = wn * 64 + jj * 16 + (lane & 15);
            const float cf = s_coef[P * 64 + rloc];
            stg[rloc * 264 + col] = __float2bfloat16(cf * (acc[ib + ii][jj][r] + bvj[jj]));
          }
    }
    __syncthreads();
    const int rr = tid >> 3;
    const int m = P * 64 + rr;
    if (m0 + m < cnt) {
      __hip_bfloat16* dst = ybuf + (size_t)(pbase + m) * DDIM + n0;
      const __hip_bfloat16* src = stg + rr * 264;
#pragma unroll
      for (int c = 0; c < 4; c++)
        *(uint4*)(dst + (tid & 7) * 8 + c * 64) = *(const uint4*)(src + (tid & 7) * 8 + c * 64);
    }
  }
}

// ---------------- combine ----------------
__global__ __launch_bounds__(256) void combine_kernel(
    const __hip_bfloat16* __restrict__ ybuf,    // [K_SEL][D]
    const unsigned* __restrict__ tcnt,
    const unsigned* __restrict__ tslot,
    const unsigned* __restrict__ exoff,
    float* __restrict__ out)                    // [S][D]
{
  const int tid = threadIdx.x;
  const int t = blockIdx.x * 2 + (tid >> 7);
  const int d0 = (tid & 127) * 8;
  float a[8] = {0, 0, 0, 0, 0, 0, 0, 0};
  const unsigned n = tcnt[t];
  for (unsigned s = 0; s < n; s++) {
    const unsigned code = tslot[t * 8u + s];
    const unsigned p = exoff[code >> 14] + (code & 16383u);
    bf16x8 v = *(const bf16x8*)(ybuf + (size_t)p * DDIM + d0);
#pragma unroll
    for (int k = 0; k < 8; k++)
      a[k] += __uint_as_float(((unsigned)(unsigned short)v[k]) << 16);
  }
  float* op = out + (size_t)t * DDIM + d0;
  *(float4*)op = make_float4(a[0], a[1], a[2], a[3]);
  *(float4*)(op + 4) = make_float4(a[4], a[5], a[6], a[7]);
}

// ---------------- launch ----------------
extern "C" void kernel_launch(void* const* d_in, const int* in_sizes, int n_in,
                              void* d_out, int out_size, void* d_ws, size_t ws_size,
                              hipStream_t stream) {
  const float* x    = (const float*)d_in[0];
  const float* gw   = (const float*)d_in[1];
  const float* bias = (const float*)d_in[2];
  const float* W1   = (const float*)d_in[3];
  const float* b1   = (const float*)d_in[4];
  const float* W2   = (const float*)d_in[5];
  const float* b2   = (const float*)d_in[6];
  float* out = (float*)d_out;
  char* ws = (char*)d_ws;

  if (ws_size < (size_t)WS_TOTAL) {
    fprintf(stderr, "kernel_launch: ws_size %zu < required %u\n", ws_size, WS_TOTAL);
    return;
  }

  unsigned* meta   = (unsigned*)(ws + WS_META);
  unsigned* hist   = (unsigned*)(ws + WS_HIST);
  unsigned* counts = (unsigned*)(ws + WS_COUNTS);
  unsigned* exoff  = (unsigned*)(ws + WS_EXOFF);
  unsigned* tiei   = (unsigned*)(ws + WS_TIEIDX);
  unsigned* tcnt   = (unsigned*)(ws + WS_TCNT);
  unsigned* tslot  = (unsigned*)(ws + WS_TSLOT);
  int*      tokl   = (int*)(ws + WS_TOK);
  float*    coefl  = (float*)(ws + WS_COEF);
  float*    scores = (float*)(ws + WS_SCORES);
  __hip_bfloat16* xb   = (__hip_bfloat16*)(ws + WS_XB);
  __hip_bfloat16* w1t  = (__hip_bfloat16*)(ws + WS_W1T);
  __hip_bfloat16* w2t  = (__hip_bfloat16*)(ws + WS_W2T);
  __hip_bfloat16* hbuf = (__hip_bfloat16*)(ws + WS_HBUF);
  __hip_bfloat16* ybuf = (__hip_bfloat16*)(ws + WS_YBUF);

  hipMemsetAsync(ws, 0, WS_CLEAR, stream);
  hipMemsetAsync(ws + WS_TCNT, 0, S_TOK * sizeof(unsigned), stream);

  transpose_bf16_kernel<<<dim3(HDIM / 32, DDIM / 32, E_EXP), dim3(32, 8), 0, stream>>>(W1, w1t, DDIM, HDIM);
  transpose_bf16_kernel<<<dim3(DDIM / 32, HDIM / 32, E_EXP), dim3(32, 8), 0, stream>>>(W2, w2t, HDIM, DDIM);

  router_kernel<<<S_TOK / 4, 256, 0, stream>>>(x, gw, bias, scores, xb);

  for (int p = 0; p < 4; p++) {
    hist_pass_kernel<<<ES / 2048, 256, 0, stream>>>(scores, meta, hist + p * 256, p);
    scan_pass_kernel<<<1, 256, 0, stream>>>(hist + p * 256, meta, p == 3);
  }
  sel_kernel<<<ES / 256, 256, 0, stream>>>(scores, meta, counts, tokl, coefl, tiei, tcnt, tslot);
  fin_kernel<<<1, 256, 0, stream>>>(meta, tiei, counts, tokl, coefl, tcnt, tslot);
  tail_kernel<<<1, 64, 0, stream>>>(counts, exoff, out + OUT_XO);

  gemm1_kernel<<<8192, 512, 0, stream>>>(xb, w1t, b1, tokl, counts, exoff, hbuf);
  gemm2_kernel<<<2048, 512, 0, stream>>>(hbuf, w2t, b2, coefl, counts, exoff, ybuf);
  combine_kernel<<<S_TOK / 2, 256, 0, stream>>>(ybuf, tcnt, tslot, exoff, out);
}